// Round 17
// baseline (199.752 us; speedup 1.0000x reference)
//
#include <hip/hip_runtime.h>

#define NN 4096
#define DD 128
#define BB 128
#define QQ 5
#define MAXDEG 96
#define SRCF 0x40000000
#define HP 136   // ushort pitch for bf16 operand buffers: 272B rows -> +4 banks/row
#define FP 132   // float pitch for f32 operand buffers: 528B rows -> +4 banks/row
#define CCAP 1024 // LDS-resident compact correction entries (8 KB)

typedef __attribute__((ext_vector_type(8))) short bf16x8;
typedef __attribute__((ext_vector_type(4))) float f32x4;

// LDS-only barrier: order ds ops, sync waves, never drain vmcnt.
#define LBAR() do { asm volatile("s_waitcnt lgkmcnt(0)" ::: "memory"); \
                    __builtin_amdgcn_sched_barrier(0); \
                    __builtin_amdgcn_s_barrier(); \
                    __builtin_amdgcn_sched_barrier(0); } while (0)

__device__ __forceinline__ float dot4f(float4 a, float4 b) {
    return a.x*b.x + a.y*b.y + a.z*b.z + a.w*b.w;
}
__device__ __forceinline__ unsigned short bfr(float x) {
    unsigned u = __float_as_uint(x);
    return (unsigned short)((u + 0x7fffu + ((u >> 16) & 1u)) >> 16);
}
__device__ __forceinline__ unsigned int pack2bf(float lo, float hi) {
    return ((unsigned int)bfr(hi) << 16) | (unsigned int)bfr(lo);
}

// ---------------- neighbor-list precompute (parallel) ----------------
__global__ void nbr_kernel(const int* __restrict__ u, const int* __restrict__ v,
                           const float* __restrict__ A, const float* __restrict__ S,
                           int* __restrict__ nbr_cnt, int2* __restrict__ nbr_pack)
{
    __shared__ int   lcnt[257];
    __shared__ int   sidx[MAXDEG];
    __shared__ float sq[MAXDEG];
    __shared__ float ssum;
    __shared__ int   stot;

    const int p    = blockIdx.x;
    const int i    = p >> 1;
    const int side = p & 1;
    const int other = (side == 0) ? v[i] : u[i];
    const float* Arow = A + (size_t)other * NN;
    const float* Srow = S + (size_t)other * NN;
    const int tid = threadIdx.x;

    const int base = tid * 16;
    int c0 = 0;
    for (int j = 0; j < 16; ++j) c0 += (Arow[base + j] > 0.0f) ? 1 : 0;
    lcnt[tid] = c0;
    __syncthreads();
    if (tid == 0) {
        int s = 0;
        for (int k = 0; k < 256; ++k) { int c = lcnt[k]; lcnt[k] = s; s += c; }
        stot = s;
    }
    __syncthreads();
    int off = lcnt[tid];
    for (int j = 0; j < 16; ++j) {
        if (Arow[base + j] > 0.0f) {
            if (off < MAXDEG) sidx[off] = base + j;
            ++off;
        }
    }
    __syncthreads();
    int cnt = stot; if (cnt > MAXDEG) cnt = MAXDEG;
    for (int jj = tid; jj < cnt; jj += 256) sq[jj] = expf(Srow[sidx[jj]]);
    __syncthreads();
    if (tid == 0) {
        float s = 0.0f;
        for (int jj = 0; jj < cnt; ++jj) s += sq[jj];
        ssum = s + 1e-7f;
    }
    __syncthreads();
    for (int jj = tid; jj < cnt; jj += 256) {
        int2 pk;
        pk.x = sidx[jj];
        pk.y = __float_as_int(sq[jj] / ssum);
        nbr_pack[p * MAXDEG + jj] = pk;
    }
    if (tid == 0) nbr_cnt[p] = cnt;
}

// ---------------- Whz0[n][d] = z0[n].Wh[d] + bh[d] ----------------
__global__ __launch_bounds__(512) void whz_init(
    const float* __restrict__ z0, const float* __restrict__ Wh, const float* __restrict__ bh,
    float* __restrict__ Whz0)
{
    const int t   = threadIdx.x;
    const int rep = t & 7;
    const int d0  = t >> 3;
    float4 wh0[4], wh1[4];
    #pragma unroll
    for (int m = 0; m < 4; ++m) {
        wh0[m] = *(const float4*)(Wh + (size_t)d0*DD + rep*16 + m*4);
        wh1[m] = *(const float4*)(Wh + (size_t)(d0+64)*DD + rep*16 + m*4);
    }
    const float bh0 = bh[d0], bh1 = bh[d0+64];
    const int r0 = blockIdx.x * 16;
    for (int r = r0; r < r0 + 16; ++r) {
        const float* zr = z0 + (size_t)r*DD + rep*16;
        float a0 = 0.f, a1 = 0.f;
        #pragma unroll
        for (int m = 0; m < 4; ++m) {
            float4 zz = *(const float4*)(zr + m*4);
            a0 += dot4f(zz, wh0[m]);
            a1 += dot4f(zz, wh1[m]);
        }
        a0 += __shfl_xor(a0,1); a0 += __shfl_xor(a0,2); a0 += __shfl_xor(a0,4);
        a1 += __shfl_xor(a1,1); a1 += __shfl_xor(a1,2); a1 += __shfl_xor(a1,4);
        if (rep == 0) {
            Whz0[(size_t)r*DD + d0]    = a0 + bh0;
            Whz0[(size_t)r*DD + d0+64] = a1 + bh1;
        }
    }
}

// ---------------- last-update sources for u,v,neg rows ----------------
__global__ void src_kernel(const int* __restrict__ u, const int* __restrict__ v,
                           const int* __restrict__ neg,
                           int* __restrict__ zsrc, int* __restrict__ negsrc)
{
    const int i = blockIdx.x;
    const int k = threadIdx.x;
    if (k >= 2 + 2*QQ) return;
    const int n = (k == 0) ? u[i] : (k == 1) ? v[i] : neg[i*2*QQ + (k-2)];
    int s = n;
    for (int j = i-1; j >= 0; --j) {
        if (v[j] == n) { s = SRCF | (j*2 + 1); break; }
        if (u[j] == n) { s = SRCF | (j*2 + 0); break; }
    }
    if (k < 2) zsrc[i*2 + k] = s;
    else       negsrc[i*2*QQ + (k-2)] = s;
}

// ---------------- static-max + correction lists per (i,side) ----------------
__global__ void prep_kernel(const int* __restrict__ u, const int* __restrict__ v,
                            const int* __restrict__ nbr_cnt, const int2* __restrict__ nbr_pack,
                            const float* __restrict__ Whz0,
                            float* __restrict__ maxpre, int* __restrict__ ncorr,
                            int2* __restrict__ corr_pack)
{
    __shared__ int   su[BB], sv[BB];
    __shared__ int   sidx[MAXDEG];
    __shared__ float sq[MAXDEG];
    __shared__ unsigned char cflag[MAXDEG];
    __shared__ int ccnt;

    const int p   = blockIdx.x;
    const int i   = p >> 1;
    const int tid = threadIdx.x;
    if (tid < BB) { su[tid] = u[tid]; sv[tid] = v[tid]; }
    if (tid == 0) ccnt = 0;
    const int cnt = nbr_cnt[p];
    for (int jj = tid; jj < cnt; jj += 128) {
        int2 pk = nbr_pack[p*MAXDEG + jj];
        sidx[jj] = pk.x; sq[jj] = __int_as_float(pk.y);
    }
    __syncthreads();
    for (int jj = tid; jj < cnt; jj += 128) {
        const int r = sidx[jj];
        int fs = -1;
        for (int j = i-1; j >= 0; --j) {
            if (sv[j] == r) { fs = j*2 + 1; break; }
            if (su[j] == r) { fs = j*2 + 0; break; }
        }
        if (fs >= 0) {
            const int pos = atomicAdd(&ccnt, 1);   // order-free (commutative max fold)
            int2 cp; cp.x = fs; cp.y = __float_as_int(sq[jj]);
            corr_pack[p*MAXDEG + pos] = cp;
            cflag[jj] = 1;
        } else cflag[jj] = 0;
    }
    __syncthreads();
    const int d = tid;
    float m = -3.0e38f;
    for (int jj = 0; jj < cnt; ++jj)
        if (!cflag[jj]) m = fmaxf(m, sq[jj] * Whz0[(size_t)sidx[jj]*DD + d]);
    maxpre[(size_t)p*DD + d] = m;
    if (tid == 0) ncorr[p] = ccnt;
}

// ---------------- pair dependency flags ----------------
__global__ void pair_kernel(const int* __restrict__ zsrc, const int* __restrict__ ncorr,
                            const int2* __restrict__ corr_pack, int* __restrict__ pdep)
{
    const int g = blockIdx.x;
    const int tid = threadIdx.x;
    const int Astep = 2*g, Bstep = 2*g+1;
    __shared__ int dep;
    if (tid == 0) dep = 0;
    __syncthreads();
    if (tid < 2) {
        const int s = zsrc[Bstep*2 + tid];
        if ((s & SRCF) && (((s & 0xFFFF) >> 1) == Astep)) atomicOr(&dep, 1);
    }
    for (int k = 0; k < 2; ++k) {
        const int p = Bstep*2 + k;
        const int nc = ncorr[p];
        for (int c = tid; c < nc; c += 64)
            if ((corr_pack[p*MAXDEG + c].x >> 1) == Astep) atomicOr(&dep, 1);
    }
    __syncthreads();
    if (tid == 0) pdep[g] = dep;
}

// ---------------- compact corrections: exclusive scan + pack (for LDS residency) ----------------
__global__ void compact_kernel(const int* __restrict__ ncorr, const int2* __restrict__ corr_pack,
                               int* __restrict__ corr_off, int2* __restrict__ corr_compact)
{
    __shared__ int off_s[257];
    const int tid = threadIdx.x;     // 0..255
    if (tid == 0) {
        int s = 0;
        for (int p = 0; p < 2*BB; ++p) { off_s[p] = s; s += ncorr[p]; }
        off_s[2*BB] = s;
    }
    __syncthreads();
    corr_off[tid] = off_s[tid];
    if (tid == 0) corr_off[2*BB] = off_s[2*BB];
    const int p = tid;
    const int b0 = off_s[p];
    const int nc = off_s[p+1] - b0;
    for (int c = 0; c < nc; ++c)
        corr_compact[b0 + c] = corr_pack[p*MAXDEG + c];
}

// ---------------- sequential scan: 64 paired groups, LDS-resident corrections ----------------
__global__ __launch_bounds__(512) void scan_kernel(
    const float* __restrict__ z0, const float* __restrict__ time_diff,
    const int* __restrict__ nbr_cnt, const int* __restrict__ ncorr,
    const int* __restrict__ corr_off, const int2* __restrict__ corr_compact,
    const float* __restrict__ maxpre, const int* __restrict__ zsrc,
    const int* __restrict__ pdep,
    const float* __restrict__ Wh,  const float* __restrict__ bh,
    const float* __restrict__ Wst, const float* __restrict__ bst,
    const float* __restrict__ Wrc, const float* __restrict__ brc,
    const float* __restrict__ Wt,  const float* __restrict__ bt,
    float* __restrict__ zlog)
{
    __shared__ __align__(16) unsigned short whz_sb[2*BB*DD];   // 64 KB whz log (bf16)
    __shared__ __align__(16) unsigned short zlog_sb[2*BB*DD];  // 64 KB z log (bf16)
    __shared__ __align__(16) unsigned short h_b[4][HP];
    __shared__ __align__(16) unsigned short zrow_b[4][HP];
    __shared__ __align__(16) unsigned short zupdb[4][HP];
    __shared__ __align__(16) float zupd_s[4][FP];
    __shared__ __align__(16) float tdw_s[4][FP];
    __shared__ __align__(16) float tdi_s[BB*8];
    __shared__ __align__(16) int2 corr_lds[CCAP];              // 8 KB compact corrections
    __shared__ int corr_off_s[2*BB + 1];
    __shared__ int cnt_s[2*BB], zsrc_s[2*BB];
    __shared__ int pdep_s[BB/2];
    __shared__ int defflag[4];

    const int t    = threadIdx.x;
    const int wv   = t >> 6;
    const int ln   = t & 63;
    const int arow = wv*16 + (ln & 15);
    const int kgrp = ln >> 4;
    const int ncol = ln & 15;
    const int dbase = wv*16 + kgrp*4;

    // ---- persistent A-fragments (packed bf16 -> remat-proof) ----
    bf16x8 afw[8];   // [Wst | Wrc], K=256
    #pragma unroll
    for (int kt = 0; kt < 8; ++kt) {
        const int kb = kt*32 + kgrp*8;
        const float* src = (kb < 128) ? (Wst + (size_t)arow*DD + kb)
                                      : (Wrc + (size_t)arow*DD + (kb - 128));
        #pragma unroll
        for (int j = 0; j < 8; ++j) afw[kt][j] = (short)bfr(src[j]);
    }
    bf16x8 afh[4];   // Wh, K=128
    #pragma unroll
    for (int kt = 0; kt < 4; ++kt) {
        const float* src = Wh + (size_t)arow*DD + kt*32 + kgrp*8;
        #pragma unroll
        for (int j = 0; j < 8; ++j) afh[kt][j] = (short)bfr(src[j]);
    }
    f32x4 bsv, bhv;
    #pragma unroll
    for (int r = 0; r < 4; ++r) {
        bsv[r] = bst[dbase+r] + brc[dbase+r] + bt[dbase+r];
        bhv[r] = bh[dbase+r];
    }
    const float4 wtA = *(const float4*)(Wt + (size_t)(ln*2)*4);
    const float4 wtB = *(const float4*)(Wt + (size_t)(ln*2+1)*4);

    // ---- one-time LDS preloads ----
    if (t < 256)      { cnt_s[t] = nbr_cnt[t]; }
    else              { zsrc_s[t-256] = zsrc[t-256]; }
    if (t < BB/2)     pdep_s[t] = pdep[t];
    if (t < 4)        defflag[t] = 0;
    for (int e = t; e < 2*BB + 1; e += 512) corr_off_s[e] = corr_off[e];
    {
        const int ctotal = corr_off[2*BB];
        const int ctot = (ctotal < CCAP) ? ctotal : CCAP;
        for (int e = t; e < ctot; e += 512) corr_lds[e] = corr_compact[e];
    }
    {
        const float sdv[4] = {50.f, 7.f, 15.f, 15.f};
        for (int e = t; e < BB*8; e += 512) tdi_s[e] = time_diff[e] / sdv[e & 3];
    }
    __syncthreads();

    // ---- wave-private pipeline state ----
    float2 mwork = make_float2(0.f, 0.f);
    float2 mnext = make_float2(0.f, 0.f);
    int2 de0, de1, de2, de3; int ndefr = 0;
    int2 ie0, ie1;           int nintra = 0;
    float2 zn2 = make_float2(0.f, 0.f);

    // ================= helper lambdas =================
    auto DO_P1 = [&]() {
        const int cc = (ncol < 4) ? ncol : 0;
        const unsigned short* hp = &h_b[cc][0];
        const unsigned short* zp = &zrow_b[cc][0];
        f32x4 accA = {0.f,0.f,0.f,0.f}, accB = {0.f,0.f,0.f,0.f};
        __builtin_amdgcn_s_setprio(1);
        #pragma unroll
        for (int kt = 0; kt < 4; kt += 2) {
            bf16x8 b0 = *(const bf16x8*)&hp[kt*32 + kgrp*8];
            bf16x8 b1 = *(const bf16x8*)&hp[(kt+1)*32 + kgrp*8];
            accA = __builtin_amdgcn_mfma_f32_16x16x32_bf16(afw[kt],   b0, accA, 0,0,0);
            accB = __builtin_amdgcn_mfma_f32_16x16x32_bf16(afw[kt+1], b1, accB, 0,0,0);
        }
        #pragma unroll
        for (int kt = 4; kt < 8; kt += 2) {
            bf16x8 b0 = *(const bf16x8*)&zp[(kt-4)*32 + kgrp*8];
            bf16x8 b1 = *(const bf16x8*)&zp[(kt-3)*32 + kgrp*8];
            accA = __builtin_amdgcn_mfma_f32_16x16x32_bf16(afw[kt],   b0, accA, 0,0,0);
            accB = __builtin_amdgcn_mfma_f32_16x16x32_bf16(afw[kt+1], b1, accB, 0,0,0);
        }
        __builtin_amdgcn_s_setprio(0);
        if (ncol < 4) {
            const f32x4 tdwv = *(const f32x4*)&tdw_s[ncol][dbase];
            f32x4 zu4;
            #pragma unroll
            for (int r = 0; r < 4; ++r) {
                const float a = accA[r] + accB[r] + bsv[r] + tdwv[r];
                zu4[r] = 1.0f/(1.0f + __expf(-a));
            }
            *(f32x4*)&zupd_s[ncol][dbase] = zu4;
            uint2 pk;
            pk.x = pack2bf(zu4[0], zu4[1]);
            pk.y = pack2bf(zu4[2], zu4[3]);
            *(uint2*)&zupdb[ncol][dbase] = pk;
        }
    };

    auto DO_P2 = [&](int writeAll, int G) {
        const int cc = (ncol < 4) ? ncol : 0;
        const unsigned short* up = &zupdb[cc][0];
        f32x4 accA = {0.f,0.f,0.f,0.f}, accB = {0.f,0.f,0.f,0.f};
        __builtin_amdgcn_s_setprio(1);
        {
            bf16x8 b0 = *(const bf16x8*)&up[0*32 + kgrp*8];
            bf16x8 b1 = *(const bf16x8*)&up[1*32 + kgrp*8];
            bf16x8 b2 = *(const bf16x8*)&up[2*32 + kgrp*8];
            bf16x8 b3 = *(const bf16x8*)&up[3*32 + kgrp*8];
            accA = __builtin_amdgcn_mfma_f32_16x16x32_bf16(afh[0], b0, accA, 0,0,0);
            accB = __builtin_amdgcn_mfma_f32_16x16x32_bf16(afh[1], b1, accB, 0,0,0);
            accA = __builtin_amdgcn_mfma_f32_16x16x32_bf16(afh[2], b2, accA, 0,0,0);
            accB = __builtin_amdgcn_mfma_f32_16x16x32_bf16(afh[3], b3, accB, 0,0,0);
        }
        __builtin_amdgcn_s_setprio(0);
        if (ncol < 4 && (writeAll || ncol < 2)) {
            const int row = 4*G + ncol;
            uint2 wpk;
            wpk.x = pack2bf(accA[0]+accB[0]+bhv[0], accA[1]+accB[1]+bhv[1]);
            wpk.y = pack2bf(accA[2]+accB[2]+bhv[2], accA[3]+accB[3]+bhv[3]);
            *(uint2*)&whz_sb[row*DD + dbase] = wpk;
            const f32x4 zu4 = *(const f32x4*)&zupd_s[ncol][dbase];
            uint2 zpk;
            zpk.x = pack2bf(zu4[0], zu4[1]);
            zpk.y = pack2bf(zu4[2], zu4[3]);
            *(uint2*)&zlog_sb[row*DD + dbase] = zpk;
        }
    };

    // Prepare pair curG+1 = steps {C, C+1}; corrections read from LDS.
    auto PREP = [&](int curG) {
        const int C = 2*curG + 2;
        if (C >= BB) return;
        if (wv < 4) {
            const int step = C + (wv >> 1);
            const int side = wv & 1;
            const int p1 = step*2 + side;
            const int cbase = corr_off_s[p1];
            const int nc = corr_off_s[p1+1] - cbase;
            float2 m = mnext;
            int nd = 0, ni = 0;
            int2 dl0, dl1, dl2, dl3, il0, il1;
            for (int c = 0; c < nc; ++c) {
                const int idx = cbase + c;
                const int2 e = (idx < CCAP) ? corr_lds[idx] : corr_compact[idx];
                if ((e.x >> 2) == curG) {                       // src in current pair -> defer
                    if (nd==0) dl0=e; else if (nd==1) dl1=e; else if (nd==2) dl2=e; else dl3=e;
                    ++nd;
                } else if ((e.x >> 1) == C && step == C+1) {    // intra-next-pair
                    if (ni==0) il0=e; else il1=e;
                    ++ni;
                } else {
                    const float qc = __int_as_float(e.y);
                    const unsigned pk = *(const unsigned*)&whz_sb[e.x*DD + ln*2];
                    m.x = fmaxf(m.x, qc * __uint_as_float(pk << 16));
                    m.y = fmaxf(m.y, qc * __uint_as_float(pk & 0xffff0000u));
                }
            }
            mwork = m; ndefr = nd; nintra = ni;
            de0=dl0; de1=dl1; de2=dl2; de3=dl3; ie0=il0; ie1=il1;
            if (nd == 0 && ni == 0) {
                float h0 = 0.f, h1 = 0.f;
                if (cnt_s[p1] > 0) {
                    h0 = 1.0f/(1.0f + __expf(-m.x));
                    h1 = 1.0f/(1.0f + __expf(-m.y));
                }
                *(unsigned*)&h_b[wv][ln*2] = pack2bf(h0, h1);
            }
            if (ln == 0) defflag[wv] = nd;
            const int Cn = C + 2;
            const int stepn = (Cn + (wv>>1) < BB) ? (Cn + (wv>>1)) : step;
            const int pn = stepn*2 + side;
            mnext = *(const float2*)&maxpre[(size_t)pn*DD + ln*2];
        } else {
            const int k = wv - 4;
            const int step = C + (k >> 1);
            const int uvk = k & 1;
            const int s = zsrc_s[step*2 + uvk];
            if (s & SRCF) {
                const int row = s & 0xFFFF;
                const int rg  = row >> 2;
                if (rg == curG) {
                    const float2 zf = *(const float2*)&zupd_s[row & 3][ln*2];
                    *(unsigned*)&zrow_b[k][ln*2] = pack2bf(zf.x, zf.y);
                } else if (rg < curG) {
                    *(unsigned*)&zrow_b[k][ln*2] = *(const unsigned*)&zlog_sb[row*DD + ln*2];
                }
                // rg == curG+1 (B references A of the NEXT pair): slow path republishes
            } else {
                *(unsigned*)&zrow_b[k][ln*2] = pack2bf(zn2.x, zn2.y);
            }
            if (wv == 4) {
                const float* tp = &tdi_s[C*8];
                tdw_s[0][ln*2]   = tp[0]*wtA.x + tp[1]*wtA.y + tp[2]*wtA.z + tp[3]*wtA.w;
                tdw_s[0][ln*2+1] = tp[0]*wtB.x + tp[1]*wtB.y + tp[2]*wtB.z + tp[3]*wtB.w;
                tdw_s[1][ln*2]   = tp[4]*wtA.x + tp[5]*wtA.y + tp[6]*wtA.z + tp[7]*wtA.w;
                tdw_s[1][ln*2+1] = tp[4]*wtB.x + tp[5]*wtB.y + tp[6]*wtB.z + tp[7]*wtB.w;
            } else if (wv == 5) {
                const float* tp = &tdi_s[(C+1)*8];
                tdw_s[2][ln*2]   = tp[0]*wtA.x + tp[1]*wtA.y + tp[2]*wtA.z + tp[3]*wtA.w;
                tdw_s[2][ln*2+1] = tp[0]*wtB.x + tp[1]*wtB.y + tp[2]*wtB.z + tp[3]*wtB.w;
                tdw_s[3][ln*2]   = tp[4]*wtA.x + tp[5]*wtA.y + tp[6]*wtA.z + tp[7]*wtA.w;
                tdw_s[3][ln*2+1] = tp[4]*wtB.x + tp[5]*wtB.y + tp[6]*wtB.z + tp[7]*wtB.w;
            }
            const int Cn = C + 2;
            if (Cn + (k>>1) < BB) {
                const int sn = zsrc_s[(Cn + (k>>1))*2 + uvk];
                if (!(sn & SRCF)) zn2 = *(const float2*)&z0[(size_t)sn*DD + ln*2];
            }
        }
    };

    // ---- priming: prefetch + prepare pair 0 ----
    if (wv < 4) {
        const int p0 = (wv >> 1)*2 + (wv & 1);
        mnext = *(const float2*)&maxpre[(size_t)p0*DD + ln*2];
    } else {
        const int k = wv - 4;
        const int s = zsrc_s[(k >> 1)*2 + (k & 1)];
        if (!(s & SRCF)) zn2 = *(const float2*)&z0[(size_t)s*DD + ln*2];
    }
    // ensure mnext/zn2 loads complete before PREP(-1) uses them (compiler waits at use)
    PREP(-1);
    LBAR();

    // ================= main loop over 64 pairs =================
    for (int G = 0; G < BB/2; ++G) {
        // ---- FIXUP: fold deferred cross-pair corrections ----
        if (defflag[0] | defflag[1] | defflag[2] | defflag[3]) {
            if (wv < 4 && ndefr) {
                float2 m = mwork;
                {
                    const float qc = __int_as_float(de0.y);
                    const unsigned pk = *(const unsigned*)&whz_sb[de0.x*DD + ln*2];
                    m.x = fmaxf(m.x, qc * __uint_as_float(pk << 16));
                    m.y = fmaxf(m.y, qc * __uint_as_float(pk & 0xffff0000u));
                }
                if (ndefr > 1) {
                    const float qc = __int_as_float(de1.y);
                    const unsigned pk = *(const unsigned*)&whz_sb[de1.x*DD + ln*2];
                    m.x = fmaxf(m.x, qc * __uint_as_float(pk << 16));
                    m.y = fmaxf(m.y, qc * __uint_as_float(pk & 0xffff0000u));
                }
                if (ndefr > 2) {
                    const float qc = __int_as_float(de2.y);
                    const unsigned pk = *(const unsigned*)&whz_sb[de2.x*DD + ln*2];
                    m.x = fmaxf(m.x, qc * __uint_as_float(pk << 16));
                    m.y = fmaxf(m.y, qc * __uint_as_float(pk & 0xffff0000u));
                }
                if (ndefr > 3) {
                    const float qc = __int_as_float(de3.y);
                    const unsigned pk = *(const unsigned*)&whz_sb[de3.x*DD + ln*2];
                    m.x = fmaxf(m.x, qc * __uint_as_float(pk << 16));
                    m.y = fmaxf(m.y, qc * __uint_as_float(pk & 0xffff0000u));
                }
                mwork = m; ndefr = 0;
                if (nintra == 0) {
                    const int p1 = (2*G + (wv>>1))*2 + (wv & 1);
                    float h0 = 0.f, h1 = 0.f;
                    if (cnt_s[p1] > 0) {
                        h0 = 1.0f/(1.0f + __expf(-m.x));
                        h1 = 1.0f/(1.0f + __expf(-m.y));
                    }
                    *(unsigned*)&h_b[wv][ln*2] = pack2bf(h0, h1);
                }
            }
            LBAR();
        }

        if (!pdep_s[G]) {
            // -------- fast path: 2 phases for 2 steps --------
            DO_P1();
            LBAR();
            DO_P2(1, G);
            PREP(G);
            LBAR();
        } else {
            // -------- slow path: step A then step B --------
            DO_P1();
            LBAR();
            DO_P2(0, G);
            if (wv >= 6) {
                const int k = wv - 4;
                const int s = zsrc_s[(2*G+1)*2 + (k & 1)];
                if ((s & SRCF) && (((s & 0xFFFF) >> 2) == G)) {
                    const int row = s & 0xFFFF;
                    const float2 zf = *(const float2*)&zupd_s[row & 3][ln*2];
                    *(unsigned*)&zrow_b[k][ln*2] = pack2bf(zf.x, zf.y);
                }
            }
            LBAR();
            if ((wv == 2 || wv == 3) && nintra) {
                float2 m = mwork;
                {
                    const float qc = __int_as_float(ie0.y);
                    const unsigned pk = *(const unsigned*)&whz_sb[ie0.x*DD + ln*2];
                    m.x = fmaxf(m.x, qc * __uint_as_float(pk << 16));
                    m.y = fmaxf(m.y, qc * __uint_as_float(pk & 0xffff0000u));
                }
                if (nintra > 1) {
                    const float qc = __int_as_float(ie1.y);
                    const unsigned pk = *(const unsigned*)&whz_sb[ie1.x*DD + ln*2];
                    m.x = fmaxf(m.x, qc * __uint_as_float(pk << 16));
                    m.y = fmaxf(m.y, qc * __uint_as_float(pk & 0xffff0000u));
                }
                const int p1 = (2*G+1)*2 + (wv & 1);
                float h0 = 0.f, h1 = 0.f;
                if (cnt_s[p1] > 0) {
                    h0 = 1.0f/(1.0f + __expf(-m.x));
                    h1 = 1.0f/(1.0f + __expf(-m.y));
                }
                *(unsigned*)&h_b[wv][ln*2] = pack2bf(h0, h1);
                nintra = 0;
            }
            LBAR();
            DO_P1();
            LBAR();
            DO_P2(1, G);
            PREP(G);
            LBAR();
        }
    }

    // ---- batched zlog dump (only global store in the kernel) ----
    for (int e = t; e < BB*DD; e += 512) {
        const unsigned pk = *(const unsigned*)&zlog_sb[e*2];
        float2 val;
        val.x = __uint_as_float(pk << 16);
        val.y = __uint_as_float(pk & 0xffff0000u);
        *(float2*)&zlog[(size_t)e*2] = val;
    }
}

// ---------------- intensity epilogue (parallel, reads via src indices) ----------------
__global__ void lam_kernel(const float* __restrict__ z0, const float* __restrict__ zlog,
                           const int* __restrict__ zsrc, const int* __restrict__ negsrc,
                           const int* __restrict__ et,
                           const float* __restrict__ w0, const float* __restrict__ b0,
                           const float* __restrict__ w1, const float* __restrict__ b1,
                           const float* __restrict__ psi,
                           float* __restrict__ out)
{
    const int b   = blockIdx.x;
    const int i   = b / 11;
    const int col = b % 11;
    const int l   = threadIdx.x;

    auto rp = [&](int s) -> const float* {
        return (s & SRCF) ? (zlog + (size_t)(s & 0xFFFF)*DD) : (z0 + (size_t)s*DD);
    };
    const float* xu;
    const float* xv;
    if (col == 0) { xu = rp(zsrc[i*2]); xv = rp(zsrc[i*2+1]); }
    else {
        const int k = col - 1;
        xu = (k < QQ) ? rp(zsrc[i*2])            : rp(negsrc[i*2*QQ + k]);
        xv = (k < QQ) ? rp(negsrc[i*2*QQ + k])   : rp(zsrc[i*2+1]);
    }
    float g0 = xu[l]*w0[l] + xu[l+64]*w0[l+64] + xv[l]*w0[DD+l] + xv[l+64]*w0[DD+l+64];
    float g1 = xu[l]*w1[l] + xu[l+64]*w1[l+64] + xv[l]*w1[DD+l] + xv[l+64]*w1[DD+l+64];
    #pragma unroll
    for (int s = 32; s >= 1; s >>= 1) { g0 += __shfl_xor(g0, s); g1 += __shfl_xor(g1, s); }
    if (l == 0) {
        g0 += b0[0]; g1 += b1[0];
        const float p0 = psi[0], p1 = psi[1];
        float r;
        if (col == 0) {
            const int e = et[i];
            const float g = e ? g1 : g0;
            const float p = e ? p1 : p0;
            const float y = g / (p + 1e-7f);
            r = p * (fmaxf(y, 0.f) + log1pf(expf(-fabsf(y))));
        } else {
            const float y0 = g0 / (p0 + 1e-7f);
            const float y1 = g1 / (p1 + 1e-7f);
            r = p0 * (fmaxf(y0, 0.f) + log1pf(expf(-fabsf(y0))))
              + p1 * (fmaxf(y1, 0.f) + log1pf(expf(-fabsf(y1))));
        }
        out[i*11 + col] = r;
    }
}

extern "C" void kernel_launch(void* const* d_in, const int* in_sizes, int n_in,
                              void* d_out, int out_size, void* d_ws, size_t ws_size,
                              hipStream_t stream)
{
    const int*   u   = (const int*)d_in[0];
    const int*   v   = (const int*)d_in[1];
    const int*   et  = (const int*)d_in[2];
    const float* td  = (const float*)d_in[3];
    const int*   neg = (const int*)d_in[4];
    const float* z0  = (const float*)d_in[5];
    const float* A   = (const float*)d_in[6];
    const float* S   = (const float*)d_in[7];
    const float* w0  = (const float*)d_in[8];
    const float* b0  = (const float*)d_in[9];
    const float* w1  = (const float*)d_in[10];
    const float* b1  = (const float*)d_in[11];
    const float* psi = (const float*)d_in[12];
    const float* Wh  = (const float*)d_in[13];
    const float* bh  = (const float*)d_in[14];
    const float* Wst = (const float*)d_in[15];
    const float* bst = (const float*)d_in[16];
    const float* Wrc = (const float*)d_in[17];
    const float* brc = (const float*)d_in[18];
    const float* Wt  = (const float*)d_in[19];
    const float* bt  = (const float*)d_in[20];

    char* ws = (char*)d_ws;
    size_t off = 0;
    auto alloc = [&](size_t bytes) {
        void* p = ws + off;
        off = (off + bytes + 255) & ~(size_t)255;
        return p;
    };
    float* Whz0   = (float*)alloc((size_t)NN*DD*sizeof(float));
    float* maxpre = (float*)alloc((size_t)2*BB*DD*sizeof(float));
    float* zlog   = (float*)alloc((size_t)2*BB*DD*sizeof(float));
    int*   ncnt   = (int*)alloc((size_t)2*BB*sizeof(int));
    int*   ncorr  = (int*)alloc((size_t)2*BB*sizeof(int));
    int2*  cpk    = (int2*)alloc((size_t)2*BB*MAXDEG*sizeof(int2));
    int*   zsrc   = (int*)alloc((size_t)2*BB*sizeof(int));
    int*   negsrc = (int*)alloc((size_t)BB*2*QQ*sizeof(int));
    int*   pdep   = (int*)alloc((size_t)(BB/2)*sizeof(int));
    int*   coff   = (int*)alloc((size_t)(2*BB+1)*sizeof(int));
    int2*  ccomp  = (int2*)alloc((size_t)2*BB*MAXDEG*sizeof(int2));
    int2*  npk    = (int2*)alloc((size_t)2*BB*MAXDEG*sizeof(int2));

    whz_init<<<NN/16, 512, 0, stream>>>(z0, Wh, bh, Whz0);
    nbr_kernel<<<2*BB, 256, 0, stream>>>(u, v, A, S, ncnt, npk);
    src_kernel<<<BB, 64, 0, stream>>>(u, v, neg, zsrc, negsrc);
    prep_kernel<<<2*BB, 128, 0, stream>>>(u, v, ncnt, npk, Whz0, maxpre, ncorr, cpk);
    pair_kernel<<<BB/2, 64, 0, stream>>>(zsrc, ncorr, cpk, pdep);
    compact_kernel<<<1, 256, 0, stream>>>(ncorr, cpk, coff, ccomp);
    scan_kernel<<<1, 512, 0, stream>>>(z0, td, ncnt, ncorr, coff, ccomp, maxpre, zsrc, pdep,
                                       Wh, bh, Wst, bst, Wrc, brc, Wt, bt, zlog);
    lam_kernel<<<BB*(1 + 2*QQ), 64, 0, stream>>>(z0, zlog, zsrc, negsrc, et,
                                                 w0, b0, w1, b1, psi, (float*)d_out);
}

// Round 18
// 193.930 us; speedup vs baseline: 1.0300x; 1.0300x over previous
//
#include <hip/hip_runtime.h>

#define NN 4096
#define DD 128
#define BB 128
#define QQ 5
#define MAXDEG 96
#define SRCF 0x40000000
#define HP 136   // ushort pitch for bf16 operand buffers: 272B rows -> +4 banks/row
#define FP 132   // float pitch for f32 operand buffers: 528B rows -> +4 banks/row
#define CCAP 1024 // LDS-resident compact correction entries (8 KB)

typedef __attribute__((ext_vector_type(8))) short bf16x8;
typedef __attribute__((ext_vector_type(4))) float f32x4;

// LDS-only barrier: order ds ops, sync waves, never drain vmcnt.
#define LBAR() do { asm volatile("s_waitcnt lgkmcnt(0)" ::: "memory"); \
                    __builtin_amdgcn_sched_barrier(0); \
                    __builtin_amdgcn_s_barrier(); \
                    __builtin_amdgcn_sched_barrier(0); } while (0)

__device__ __forceinline__ float dot4f(float4 a, float4 b) {
    return a.x*b.x + a.y*b.y + a.z*b.z + a.w*b.w;
}
__device__ __forceinline__ unsigned short bfr(float x) {
    unsigned u = __float_as_uint(x);
    return (unsigned short)((u + 0x7fffu + ((u >> 16) & 1u)) >> 16);
}
__device__ __forceinline__ unsigned int pack2bf(float lo, float hi) {
    return ((unsigned int)bfr(hi) << 16) | (unsigned int)bfr(lo);
}

// ---------------- Whz0[n][d] = z0[n].Wh[d] + bh[d] ----------------
__global__ __launch_bounds__(512) void whz_init(
    const float* __restrict__ z0, const float* __restrict__ Wh, const float* __restrict__ bh,
    float* __restrict__ Whz0)
{
    const int t   = threadIdx.x;
    const int rep = t & 7;
    const int d0  = t >> 3;
    float4 wh0[4], wh1[4];
    #pragma unroll
    for (int m = 0; m < 4; ++m) {
        wh0[m] = *(const float4*)(Wh + (size_t)d0*DD + rep*16 + m*4);
        wh1[m] = *(const float4*)(Wh + (size_t)(d0+64)*DD + rep*16 + m*4);
    }
    const float bh0 = bh[d0], bh1 = bh[d0+64];
    const int r0 = blockIdx.x * 16;
    for (int r = r0; r < r0 + 16; ++r) {
        const float* zr = z0 + (size_t)r*DD + rep*16;
        float a0 = 0.f, a1 = 0.f;
        #pragma unroll
        for (int m = 0; m < 4; ++m) {
            float4 zz = *(const float4*)(zr + m*4);
            a0 += dot4f(zz, wh0[m]);
            a1 += dot4f(zz, wh1[m]);
        }
        a0 += __shfl_xor(a0,1); a0 += __shfl_xor(a0,2); a0 += __shfl_xor(a0,4);
        a1 += __shfl_xor(a1,1); a1 += __shfl_xor(a1,2); a1 += __shfl_xor(a1,4);
        if (rep == 0) {
            Whz0[(size_t)r*DD + d0]    = a0 + bh0;
            Whz0[(size_t)r*DD + d0+64] = a1 + bh1;
        }
    }
}

// ---------------- last-update sources for u,v,neg rows ----------------
__global__ void src_kernel(const int* __restrict__ u, const int* __restrict__ v,
                           const int* __restrict__ neg,
                           int* __restrict__ zsrc, int* __restrict__ negsrc)
{
    const int i = blockIdx.x;
    const int k = threadIdx.x;
    if (k >= 2 + 2*QQ) return;
    const int n = (k == 0) ? u[i] : (k == 1) ? v[i] : neg[i*2*QQ + (k-2)];
    int s = n;
    for (int j = i-1; j >= 0; --j) {
        if (v[j] == n) { s = SRCF | (j*2 + 1); break; }
        if (u[j] == n) { s = SRCF | (j*2 + 0); break; }
    }
    if (k < 2) zsrc[i*2 + k] = s;
    else       negsrc[i*2*QQ + (k-2)] = s;
}

// ---------------- FUSED neighbor-list + static-max + corrections per (i,side) ----------------
__global__ void nbrprep_kernel(const int* __restrict__ u, const int* __restrict__ v,
                               const float* __restrict__ A, const float* __restrict__ S,
                               const float* __restrict__ Whz0,
                               float* __restrict__ maxpre, int* __restrict__ ncorr,
                               int2* __restrict__ corr_pack)
{
    __shared__ int   lcnt[257];
    __shared__ int   sidx[MAXDEG];
    __shared__ float sq[MAXDEG];
    __shared__ unsigned char cflag[MAXDEG];
    __shared__ int   su[BB], sv[BB];
    __shared__ float ssum;
    __shared__ int   stot, ccnt;

    const int p    = blockIdx.x;          // (event i, side)
    const int i    = p >> 1;
    const int side = p & 1;
    const int tid  = threadIdx.x;         // 0..255

    const int other = (side == 0) ? v[i] : u[i];   // side0 = agg(v), side1 = agg(u)
    const float* Arow = A + (size_t)other * NN;
    const float* Srow = S + (size_t)other * NN;

    // ---- phase 1: compact neighbor list (deterministic) ----
    const int base = tid * 16;
    int c0 = 0;
    for (int j = 0; j < 16; ++j) c0 += (Arow[base + j] > 0.0f) ? 1 : 0;
    lcnt[tid] = c0;
    if (tid < BB) { su[tid] = u[tid]; sv[tid] = v[tid]; }
    if (tid == 0) ccnt = 0;
    __syncthreads();
    if (tid == 0) {
        int s = 0;
        for (int k = 0; k < 256; ++k) { int c = lcnt[k]; lcnt[k] = s; s += c; }
        stot = s;
    }
    __syncthreads();
    int off = lcnt[tid];
    for (int j = 0; j < 16; ++j) {
        if (Arow[base + j] > 0.0f) {
            if (off < MAXDEG) sidx[off] = base + j;
            ++off;
        }
    }
    __syncthreads();
    const int cnt = (stot < MAXDEG) ? stot : MAXDEG;
    for (int jj = tid; jj < cnt; jj += 256) sq[jj] = expf(Srow[sidx[jj]]);
    __syncthreads();
    if (tid == 0) {
        float s = 0.0f;
        for (int jj = 0; jj < cnt; ++jj) s += sq[jj];
        ssum = s + 1e-7f;
    }
    __syncthreads();
    for (int jj = tid; jj < cnt; jj += 256) sq[jj] = sq[jj] / ssum;
    __syncthreads();

    // ---- phase 2: classify (correction vs static), emit corrections ----
    for (int jj = tid; jj < cnt; jj += 256) {
        const int r = sidx[jj];
        int fs = -1;
        for (int j = i-1; j >= 0; --j) {
            if (sv[j] == r) { fs = j*2 + 1; break; }
            if (su[j] == r) { fs = j*2 + 0; break; }
        }
        if (fs >= 0) {
            const int pos = atomicAdd(&ccnt, 1);   // order-free (commutative max fold)
            int2 cp; cp.x = fs; cp.y = __float_as_int(sq[jj]);
            corr_pack[p*MAXDEG + pos] = cp;
            cflag[jj] = 1;
        } else cflag[jj] = 0;
    }
    __syncthreads();

    // ---- phase 3: static max over never-updated neighbors ----
    if (tid < DD) {
        const int d = tid;
        float m = -3.0e38f;
        for (int jj = 0; jj < cnt; ++jj)
            if (!cflag[jj]) m = fmaxf(m, sq[jj] * Whz0[(size_t)sidx[jj]*DD + d]);
        maxpre[(size_t)p*DD + d] = m;
    }
    if (tid == 0) ncorr[p] = ccnt;
}

// ---------------- sequential scan: 64 paired groups; compaction+pdep in preamble ----------------
__global__ __launch_bounds__(512) void scan_kernel(
    const float* __restrict__ z0, const float* __restrict__ time_diff,
    const int* __restrict__ nbr_cnt_unused, const int* __restrict__ ncorr,
    const int2* __restrict__ corr_pack,
    const float* __restrict__ maxpre, const int* __restrict__ zsrc,
    const int* __restrict__ nbr_cntg,
    const float* __restrict__ Wh,  const float* __restrict__ bh,
    const float* __restrict__ Wst, const float* __restrict__ bst,
    const float* __restrict__ Wrc, const float* __restrict__ brc,
    const float* __restrict__ Wt,  const float* __restrict__ bt,
    float* __restrict__ zlog)
{
    __shared__ __align__(16) unsigned short whz_sb[2*BB*DD];   // 64 KB whz log (bf16)
    __shared__ __align__(16) unsigned short zlog_sb[2*BB*DD];  // 64 KB z log (bf16)
    __shared__ __align__(16) unsigned short h_b[4][HP];
    __shared__ __align__(16) unsigned short zrow_b[4][HP];
    __shared__ __align__(16) unsigned short zupdb[4][HP];
    __shared__ __align__(16) float zupd_s[4][FP];
    __shared__ __align__(16) float tdw_s[4][FP];
    __shared__ __align__(16) float tdi_s[BB*8];
    __shared__ __align__(16) int2 corr_lds[CCAP];              // 8 KB compact corrections
    __shared__ int corr_off_s[2*BB + 1];
    __shared__ int cnt_s[2*BB], zsrc_s[2*BB];
    __shared__ int pdep_s[BB/2];
    __shared__ int defflag[4];

    const int t    = threadIdx.x;
    const int wv   = t >> 6;
    const int ln   = t & 63;
    const int arow = wv*16 + (ln & 15);
    const int kgrp = ln >> 4;
    const int ncol = ln & 15;
    const int dbase = wv*16 + kgrp*4;

    // ---- persistent A-fragments (packed bf16 -> remat-proof) ----
    bf16x8 afw[8];   // [Wst | Wrc], K=256
    #pragma unroll
    for (int kt = 0; kt < 8; ++kt) {
        const int kb = kt*32 + kgrp*8;
        const float* src = (kb < 128) ? (Wst + (size_t)arow*DD + kb)
                                      : (Wrc + (size_t)arow*DD + (kb - 128));
        #pragma unroll
        for (int j = 0; j < 8; ++j) afw[kt][j] = (short)bfr(src[j]);
    }
    bf16x8 afh[4];   // Wh, K=128
    #pragma unroll
    for (int kt = 0; kt < 4; ++kt) {
        const float* src = Wh + (size_t)arow*DD + kt*32 + kgrp*8;
        #pragma unroll
        for (int j = 0; j < 8; ++j) afh[kt][j] = (short)bfr(src[j]);
    }
    f32x4 bsv, bhv;
    #pragma unroll
    for (int r = 0; r < 4; ++r) {
        bsv[r] = bst[dbase+r] + brc[dbase+r] + bt[dbase+r];
        bhv[r] = bh[dbase+r];
    }
    const float4 wtA = *(const float4*)(Wt + (size_t)(ln*2)*4);
    const float4 wtB = *(const float4*)(Wt + (size_t)(ln*2+1)*4);

    // ---- preamble A: scalar preloads ----
    if (t < 256)      { cnt_s[t] = nbr_cntg[t]; }
    else              { zsrc_s[t-256] = zsrc[t-256]; }
    if (t < 4)        defflag[t] = 0;
    {
        const float sdv[4] = {50.f, 7.f, 15.f, 15.f};
        for (int e = t; e < BB*8; e += 512) tdi_s[e] = time_diff[e] / sdv[e & 3];
    }
    __syncthreads();

    // ---- preamble B: prefix-scan ncorr (wave 0) -> corr_off_s ----
    if (wv == 0) {
        int n0 = ncorr[ln*4+0], n1 = ncorr[ln*4+1], n2 = ncorr[ln*4+2], n3 = ncorr[ln*4+3];
        int loc = n0 + n1 + n2 + n3;
        int incl = loc;
        #pragma unroll
        for (int s = 1; s < 64; s <<= 1) {
            int up = __shfl_up(incl, s);
            if (ln >= s) incl += up;
        }
        const int bse = incl - loc;
        corr_off_s[ln*4+0] = bse;
        corr_off_s[ln*4+1] = bse + n0;
        corr_off_s[ln*4+2] = bse + n0 + n1;
        corr_off_s[ln*4+3] = bse + n0 + n1 + n2;
        if (ln == 63) corr_off_s[256] = incl;
    }
    __syncthreads();

    // ---- preamble C: gather corrections into LDS ----
    if (t < 256) {
        const int b0 = corr_off_s[t];
        const int nc = corr_off_s[t+1] - b0;
        for (int c = 0; c < nc; ++c) {
            const int idx = b0 + c;
            if (idx < CCAP) corr_lds[idx] = corr_pack[t*MAXDEG + c];
        }
    }
    __syncthreads();

    // ---- preamble D: pair-dependency flags ----
    if (t < BB/2) {
        const int g = t;
        int dep = 0;
        #pragma unroll
        for (int k = 0; k < 2; ++k) {
            const int s = zsrc_s[(2*g+1)*2 + k];
            if ((s & SRCF) && (((s & 0xFFFF) >> 1) == 2*g)) dep = 1;
        }
        #pragma unroll
        for (int k = 0; k < 2; ++k) {
            const int p = (2*g+1)*2 + k;
            const int b0 = corr_off_s[p];
            const int nc = corr_off_s[p+1] - b0;
            for (int c = 0; c < nc; ++c) {
                const int idx = b0 + c;
                const int2 e = (idx < CCAP) ? corr_lds[idx] : corr_pack[p*MAXDEG + c];
                if ((e.x >> 1) == 2*g) dep = 1;
            }
        }
        pdep_s[g] = dep;
    }
    __syncthreads();

    // ---- wave-private pipeline state ----
    float2 mwork = make_float2(0.f, 0.f);
    float2 mnext = make_float2(0.f, 0.f);
    int2 de0, de1, de2, de3; int ndefr = 0;
    int2 ie0, ie1;           int nintra = 0;
    float2 zn2 = make_float2(0.f, 0.f);

    // ================= helper lambdas =================
    auto DO_P1 = [&]() {
        const int cc = (ncol < 4) ? ncol : 0;
        const unsigned short* hp = &h_b[cc][0];
        const unsigned short* zp = &zrow_b[cc][0];
        f32x4 accA = {0.f,0.f,0.f,0.f}, accB = {0.f,0.f,0.f,0.f};
        __builtin_amdgcn_s_setprio(1);
        #pragma unroll
        for (int kt = 0; kt < 4; kt += 2) {
            bf16x8 b0 = *(const bf16x8*)&hp[kt*32 + kgrp*8];
            bf16x8 b1 = *(const bf16x8*)&hp[(kt+1)*32 + kgrp*8];
            accA = __builtin_amdgcn_mfma_f32_16x16x32_bf16(afw[kt],   b0, accA, 0,0,0);
            accB = __builtin_amdgcn_mfma_f32_16x16x32_bf16(afw[kt+1], b1, accB, 0,0,0);
        }
        #pragma unroll
        for (int kt = 4; kt < 8; kt += 2) {
            bf16x8 b0 = *(const bf16x8*)&zp[(kt-4)*32 + kgrp*8];
            bf16x8 b1 = *(const bf16x8*)&zp[(kt-3)*32 + kgrp*8];
            accA = __builtin_amdgcn_mfma_f32_16x16x32_bf16(afw[kt],   b0, accA, 0,0,0);
            accB = __builtin_amdgcn_mfma_f32_16x16x32_bf16(afw[kt+1], b1, accB, 0,0,0);
        }
        __builtin_amdgcn_s_setprio(0);
        if (ncol < 4) {
            const f32x4 tdwv = *(const f32x4*)&tdw_s[ncol][dbase];
            f32x4 zu4;
            #pragma unroll
            for (int r = 0; r < 4; ++r) {
                const float a = accA[r] + accB[r] + bsv[r] + tdwv[r];
                zu4[r] = 1.0f/(1.0f + __expf(-a));
            }
            *(f32x4*)&zupd_s[ncol][dbase] = zu4;
            uint2 pk;
            pk.x = pack2bf(zu4[0], zu4[1]);
            pk.y = pack2bf(zu4[2], zu4[3]);
            *(uint2*)&zupdb[ncol][dbase] = pk;
        }
    };

    auto DO_P2 = [&](int writeAll, int G) {
        const int cc = (ncol < 4) ? ncol : 0;
        const unsigned short* up = &zupdb[cc][0];
        f32x4 accA = {0.f,0.f,0.f,0.f}, accB = {0.f,0.f,0.f,0.f};
        __builtin_amdgcn_s_setprio(1);
        {
            bf16x8 b0 = *(const bf16x8*)&up[0*32 + kgrp*8];
            bf16x8 b1 = *(const bf16x8*)&up[1*32 + kgrp*8];
            bf16x8 b2 = *(const bf16x8*)&up[2*32 + kgrp*8];
            bf16x8 b3 = *(const bf16x8*)&up[3*32 + kgrp*8];
            accA = __builtin_amdgcn_mfma_f32_16x16x32_bf16(afh[0], b0, accA, 0,0,0);
            accB = __builtin_amdgcn_mfma_f32_16x16x32_bf16(afh[1], b1, accB, 0,0,0);
            accA = __builtin_amdgcn_mfma_f32_16x16x32_bf16(afh[2], b2, accA, 0,0,0);
            accB = __builtin_amdgcn_mfma_f32_16x16x32_bf16(afh[3], b3, accB, 0,0,0);
        }
        __builtin_amdgcn_s_setprio(0);
        if (ncol < 4 && (writeAll || ncol < 2)) {
            const int row = 4*G + ncol;
            uint2 wpk;
            wpk.x = pack2bf(accA[0]+accB[0]+bhv[0], accA[1]+accB[1]+bhv[1]);
            wpk.y = pack2bf(accA[2]+accB[2]+bhv[2], accA[3]+accB[3]+bhv[3]);
            *(uint2*)&whz_sb[row*DD + dbase] = wpk;
            const f32x4 zu4 = *(const f32x4*)&zupd_s[ncol][dbase];
            uint2 zpk;
            zpk.x = pack2bf(zu4[0], zu4[1]);
            zpk.y = pack2bf(zu4[2], zu4[3]);
            *(uint2*)&zlog_sb[row*DD + dbase] = zpk;
        }
    };

    // Prepare pair curG+1 = steps {C, C+1}; corrections read from LDS.
    auto PREP = [&](int curG) {
        const int C = 2*curG + 2;
        if (C >= BB) return;
        if (wv < 4) {
            const int step = C + (wv >> 1);
            const int side = wv & 1;
            const int p1 = step*2 + side;
            const int cbase = corr_off_s[p1];
            const int nc = corr_off_s[p1+1] - cbase;
            float2 m = mnext;
            int nd = 0, ni = 0;
            int2 dl0, dl1, dl2, dl3, il0, il1;
            for (int c = 0; c < nc; ++c) {
                const int idx = cbase + c;
                const int2 e = (idx < CCAP) ? corr_lds[idx] : corr_pack[p1*MAXDEG + c];
                if ((e.x >> 2) == curG) {                       // src in current pair -> defer
                    if (nd==0) dl0=e; else if (nd==1) dl1=e; else if (nd==2) dl2=e; else dl3=e;
                    ++nd;
                } else if ((e.x >> 1) == C && step == C+1) {    // intra-next-pair
                    if (ni==0) il0=e; else il1=e;
                    ++ni;
                } else {
                    const float qc = __int_as_float(e.y);
                    const unsigned pk = *(const unsigned*)&whz_sb[e.x*DD + ln*2];
                    m.x = fmaxf(m.x, qc * __uint_as_float(pk << 16));
                    m.y = fmaxf(m.y, qc * __uint_as_float(pk & 0xffff0000u));
                }
            }
            mwork = m; ndefr = nd; nintra = ni;
            de0=dl0; de1=dl1; de2=dl2; de3=dl3; ie0=il0; ie1=il1;
            if (nd == 0 && ni == 0) {
                float h0 = 0.f, h1 = 0.f;
                if (cnt_s[p1] > 0) {
                    h0 = 1.0f/(1.0f + __expf(-m.x));
                    h1 = 1.0f/(1.0f + __expf(-m.y));
                }
                *(unsigned*)&h_b[wv][ln*2] = pack2bf(h0, h1);
            }
            if (ln == 0) defflag[wv] = nd;
            const int Cn = C + 2;
            const int stepn = (Cn + (wv>>1) < BB) ? (Cn + (wv>>1)) : step;
            const int pn = stepn*2 + side;
            mnext = *(const float2*)&maxpre[(size_t)pn*DD + ln*2];
        } else {
            const int k = wv - 4;
            const int step = C + (k >> 1);
            const int uvk = k & 1;
            const int s = zsrc_s[step*2 + uvk];
            if (s & SRCF) {
                const int row = s & 0xFFFF;
                const int rg  = row >> 2;
                if (rg == curG) {
                    const float2 zf = *(const float2*)&zupd_s[row & 3][ln*2];
                    *(unsigned*)&zrow_b[k][ln*2] = pack2bf(zf.x, zf.y);
                } else if (rg < curG) {
                    *(unsigned*)&zrow_b[k][ln*2] = *(const unsigned*)&zlog_sb[row*DD + ln*2];
                }
                // rg == curG+1 (B references A of the NEXT pair): slow path republishes
            } else {
                *(unsigned*)&zrow_b[k][ln*2] = pack2bf(zn2.x, zn2.y);
            }
            if (wv == 4) {
                const float* tp = &tdi_s[C*8];
                tdw_s[0][ln*2]   = tp[0]*wtA.x + tp[1]*wtA.y + tp[2]*wtA.z + tp[3]*wtA.w;
                tdw_s[0][ln*2+1] = tp[0]*wtB.x + tp[1]*wtB.y + tp[2]*wtB.z + tp[3]*wtB.w;
                tdw_s[1][ln*2]   = tp[4]*wtA.x + tp[5]*wtA.y + tp[6]*wtA.z + tp[7]*wtA.w;
                tdw_s[1][ln*2+1] = tp[4]*wtB.x + tp[5]*wtB.y + tp[6]*wtB.z + tp[7]*wtB.w;
            } else if (wv == 5) {
                const float* tp = &tdi_s[(C+1)*8];
                tdw_s[2][ln*2]   = tp[0]*wtA.x + tp[1]*wtA.y + tp[2]*wtA.z + tp[3]*wtA.w;
                tdw_s[2][ln*2+1] = tp[0]*wtB.x + tp[1]*wtB.y + tp[2]*wtB.z + tp[3]*wtB.w;
                tdw_s[3][ln*2]   = tp[4]*wtA.x + tp[5]*wtA.y + tp[6]*wtA.z + tp[7]*wtA.w;
                tdw_s[3][ln*2+1] = tp[4]*wtB.x + tp[5]*wtB.y + tp[6]*wtB.z + tp[7]*wtB.w;
            }
            const int Cn = C + 2;
            if (Cn + (k>>1) < BB) {
                const int sn = zsrc_s[(Cn + (k>>1))*2 + uvk];
                if (!(sn & SRCF)) zn2 = *(const float2*)&z0[(size_t)sn*DD + ln*2];
            }
        }
    };

    // ---- priming: prefetch + prepare pair 0 ----
    if (wv < 4) {
        const int p0 = (wv >> 1)*2 + (wv & 1);
        mnext = *(const float2*)&maxpre[(size_t)p0*DD + ln*2];
    } else {
        const int k = wv - 4;
        const int s = zsrc_s[(k >> 1)*2 + (k & 1)];
        if (!(s & SRCF)) zn2 = *(const float2*)&z0[(size_t)s*DD + ln*2];
    }
    PREP(-1);
    LBAR();

    // ================= main loop over 64 pairs =================
    for (int G = 0; G < BB/2; ++G) {
        // ---- FIXUP: fold deferred cross-pair corrections ----
        if (defflag[0] | defflag[1] | defflag[2] | defflag[3]) {
            if (wv < 4 && ndefr) {
                float2 m = mwork;
                {
                    const float qc = __int_as_float(de0.y);
                    const unsigned pk = *(const unsigned*)&whz_sb[de0.x*DD + ln*2];
                    m.x = fmaxf(m.x, qc * __uint_as_float(pk << 16));
                    m.y = fmaxf(m.y, qc * __uint_as_float(pk & 0xffff0000u));
                }
                if (ndefr > 1) {
                    const float qc = __int_as_float(de1.y);
                    const unsigned pk = *(const unsigned*)&whz_sb[de1.x*DD + ln*2];
                    m.x = fmaxf(m.x, qc * __uint_as_float(pk << 16));
                    m.y = fmaxf(m.y, qc * __uint_as_float(pk & 0xffff0000u));
                }
                if (ndefr > 2) {
                    const float qc = __int_as_float(de2.y);
                    const unsigned pk = *(const unsigned*)&whz_sb[de2.x*DD + ln*2];
                    m.x = fmaxf(m.x, qc * __uint_as_float(pk << 16));
                    m.y = fmaxf(m.y, qc * __uint_as_float(pk & 0xffff0000u));
                }
                if (ndefr > 3) {
                    const float qc = __int_as_float(de3.y);
                    const unsigned pk = *(const unsigned*)&whz_sb[de3.x*DD + ln*2];
                    m.x = fmaxf(m.x, qc * __uint_as_float(pk << 16));
                    m.y = fmaxf(m.y, qc * __uint_as_float(pk & 0xffff0000u));
                }
                mwork = m; ndefr = 0;
                if (nintra == 0) {
                    const int p1 = (2*G + (wv>>1))*2 + (wv & 1);
                    float h0 = 0.f, h1 = 0.f;
                    if (cnt_s[p1] > 0) {
                        h0 = 1.0f/(1.0f + __expf(-m.x));
                        h1 = 1.0f/(1.0f + __expf(-m.y));
                    }
                    *(unsigned*)&h_b[wv][ln*2] = pack2bf(h0, h1);
                }
            }
            LBAR();
        }

        if (!pdep_s[G]) {
            // -------- fast path: 2 phases for 2 steps --------
            DO_P1();
            LBAR();
            DO_P2(1, G);
            PREP(G);
            LBAR();
        } else {
            // -------- slow path: step A then step B --------
            DO_P1();
            LBAR();
            DO_P2(0, G);
            if (wv >= 6) {
                const int k = wv - 4;
                const int s = zsrc_s[(2*G+1)*2 + (k & 1)];
                if ((s & SRCF) && (((s & 0xFFFF) >> 2) == G)) {
                    const int row = s & 0xFFFF;
                    const float2 zf = *(const float2*)&zupd_s[row & 3][ln*2];
                    *(unsigned*)&zrow_b[k][ln*2] = pack2bf(zf.x, zf.y);
                }
            }
            LBAR();
            if ((wv == 2 || wv == 3) && nintra) {
                float2 m = mwork;
                {
                    const float qc = __int_as_float(ie0.y);
                    const unsigned pk = *(const unsigned*)&whz_sb[ie0.x*DD + ln*2];
                    m.x = fmaxf(m.x, qc * __uint_as_float(pk << 16));
                    m.y = fmaxf(m.y, qc * __uint_as_float(pk & 0xffff0000u));
                }
                if (nintra > 1) {
                    const float qc = __int_as_float(ie1.y);
                    const unsigned pk = *(const unsigned*)&whz_sb[ie1.x*DD + ln*2];
                    m.x = fmaxf(m.x, qc * __uint_as_float(pk << 16));
                    m.y = fmaxf(m.y, qc * __uint_as_float(pk & 0xffff0000u));
                }
                const int p1 = (2*G+1)*2 + (wv & 1);
                float h0 = 0.f, h1 = 0.f;
                if (cnt_s[p1] > 0) {
                    h0 = 1.0f/(1.0f + __expf(-m.x));
                    h1 = 1.0f/(1.0f + __expf(-m.y));
                }
                *(unsigned*)&h_b[wv][ln*2] = pack2bf(h0, h1);
                nintra = 0;
            }
            LBAR();
            DO_P1();
            LBAR();
            DO_P2(1, G);
            PREP(G);
            LBAR();
        }
    }

    // ---- batched zlog dump (only global store in the kernel) ----
    for (int e = t; e < BB*DD; e += 512) {
        const unsigned pk = *(const unsigned*)&zlog_sb[e*2];
        float2 val;
        val.x = __uint_as_float(pk << 16);
        val.y = __uint_as_float(pk & 0xffff0000u);
        *(float2*)&zlog[(size_t)e*2] = val;
    }
}

// ---------------- intensity epilogue (parallel, reads via src indices) ----------------
__global__ void lam_kernel(const float* __restrict__ z0, const float* __restrict__ zlog,
                           const int* __restrict__ zsrc, const int* __restrict__ negsrc,
                           const int* __restrict__ et,
                           const float* __restrict__ w0, const float* __restrict__ b0,
                           const float* __restrict__ w1, const float* __restrict__ b1,
                           const float* __restrict__ psi,
                           float* __restrict__ out)
{
    const int b   = blockIdx.x;
    const int i   = b / 11;
    const int col = b % 11;
    const int l   = threadIdx.x;

    auto rp = [&](int s) -> const float* {
        return (s & SRCF) ? (zlog + (size_t)(s & 0xFFFF)*DD) : (z0 + (size_t)s*DD);
    };
    const float* xu;
    const float* xv;
    if (col == 0) { xu = rp(zsrc[i*2]); xv = rp(zsrc[i*2+1]); }
    else {
        const int k = col - 1;
        xu = (k < QQ) ? rp(zsrc[i*2])            : rp(negsrc[i*2*QQ + k]);
        xv = (k < QQ) ? rp(negsrc[i*2*QQ + k])   : rp(zsrc[i*2+1]);
    }
    float g0 = xu[l]*w0[l] + xu[l+64]*w0[l+64] + xv[l]*w0[DD+l] + xv[l+64]*w0[DD+l+64];
    float g1 = xu[l]*w1[l] + xu[l+64]*w1[l+64] + xv[l]*w1[DD+l] + xv[l+64]*w1[DD+l+64];
    #pragma unroll
    for (int s = 32; s >= 1; s >>= 1) { g0 += __shfl_xor(g0, s); g1 += __shfl_xor(g1, s); }
    if (l == 0) {
        g0 += b0[0]; g1 += b1[0];
        const float p0 = psi[0], p1 = psi[1];
        float r;
        if (col == 0) {
            const int e = et[i];
            const float g = e ? g1 : g0;
            const float p = e ? p1 : p0;
            const float y = g / (p + 1e-7f);
            r = p * (fmaxf(y, 0.f) + log1pf(expf(-fabsf(y))));
        } else {
            const float y0 = g0 / (p0 + 1e-7f);
            const float y1 = g1 / (p1 + 1e-7f);
            r = p0 * (fmaxf(y0, 0.f) + log1pf(expf(-fabsf(y0))))
              + p1 * (fmaxf(y1, 0.f) + log1pf(expf(-fabsf(y1))));
        }
        out[i*11 + col] = r;
    }
}

extern "C" void kernel_launch(void* const* d_in, const int* in_sizes, int n_in,
                              void* d_out, int out_size, void* d_ws, size_t ws_size,
                              hipStream_t stream)
{
    const int*   u   = (const int*)d_in[0];
    const int*   v   = (const int*)d_in[1];
    const int*   et  = (const int*)d_in[2];
    const float* td  = (const float*)d_in[3];
    const int*   neg = (const int*)d_in[4];
    const float* z0  = (const float*)d_in[5];
    const float* A   = (const float*)d_in[6];
    const float* S   = (const float*)d_in[7];
    const float* w0  = (const float*)d_in[8];
    const float* b0  = (const float*)d_in[9];
    const float* w1  = (const float*)d_in[10];
    const float* b1  = (const float*)d_in[11];
    const float* psi = (const float*)d_in[12];
    const float* Wh  = (const float*)d_in[13];
    const float* bh  = (const float*)d_in[14];
    const float* Wst = (const float*)d_in[15];
    const float* bst = (const float*)d_in[16];
    const float* Wrc = (const float*)d_in[17];
    const float* brc = (const float*)d_in[18];
    const float* Wt  = (const float*)d_in[19];
    const float* bt  = (const float*)d_in[20];

    char* ws = (char*)d_ws;
    size_t off = 0;
    auto alloc = [&](size_t bytes) {
        void* p = ws + off;
        off = (off + bytes + 255) & ~(size_t)255;
        return p;
    };
    float* Whz0   = (float*)alloc((size_t)NN*DD*sizeof(float));
    float* maxpre = (float*)alloc((size_t)2*BB*DD*sizeof(float));
    float* zlog   = (float*)alloc((size_t)2*BB*DD*sizeof(float));
    int*   ncnt   = (int*)alloc((size_t)2*BB*sizeof(int));
    int*   ncorr  = (int*)alloc((size_t)2*BB*sizeof(int));
    int2*  cpk    = (int2*)alloc((size_t)2*BB*MAXDEG*sizeof(int2));
    int*   zsrc   = (int*)alloc((size_t)2*BB*sizeof(int));
    int*   negsrc = (int*)alloc((size_t)BB*2*QQ*sizeof(int));

    whz_init<<<NN/16, 512, 0, stream>>>(z0, Wh, bh, Whz0);
    src_kernel<<<BB, 64, 0, stream>>>(u, v, neg, zsrc, negsrc);
    // fused nbr+prep also produces per-(i,side) neighbor counts into ncnt via ncorr path:
    // (cnt lives in the same kernel; write it from tid==1)
    nbrprep_kernel<<<2*BB, 256, 0, stream>>>(u, v, A, S, Whz0, maxpre, ncorr, cpk);
    // neighbor counts: recompute cheaply here (cnt == popcount of A row) — reuse nbrprep's
    // stot by a tiny pass: ncnt[p] = (A[other] > 0) count. We instead derive it in-kernel:
    // nbrprep writes cnt into ncnt via maxpre sentinel? Simpler: dedicated tiny kernel below.
    // (cnt is needed only for the cnt>0 gate in h computation.)
    {
        // tiny kernel inline: reuse src_kernel-style launch to fill ncnt
    }
    // fill ncnt with a lightweight kernel: one block per (i,side), 256 threads
    struct Dummy {};
    // use a lambda-less approach: launch nbr count kernel
    extern __global__ void cnt_kernel(const int*, const int*, const float*, int*);
    cnt_kernel<<<2*BB, 256, 0, stream>>>(u, v, A, ncnt);
    scan_kernel<<<1, 512, 0, stream>>>(z0, td, nullptr, ncorr, cpk, maxpre, zsrc, ncnt,
                                       Wh, bh, Wst, bst, Wrc, brc, Wt, bt, zlog);
    lam_kernel<<<BB*(1 + 2*QQ), 64, 0, stream>>>(z0, zlog, zsrc, negsrc, et,
                                                 w0, b0, w1, b1, psi, (float*)d_out);
}

// ---------------- neighbor-count kernel (cnt>0 gate only) ----------------
__global__ void cnt_kernel(const int* __restrict__ u, const int* __restrict__ v,
                           const float* __restrict__ A, int* __restrict__ ncnt)
{
    __shared__ int csum;
    const int p    = blockIdx.x;
    const int i    = p >> 1;
    const int side = p & 1;
    const int other = (side == 0) ? v[i] : u[i];
    const float* Arow = A + (size_t)other * NN;
    const int tid = threadIdx.x;
    if (tid == 0) csum = 0;
    __syncthreads();
    int c0 = 0;
    for (int j = tid; j < NN; j += 256) c0 += (Arow[j] > 0.0f) ? 1 : 0;
    c0 += __shfl_xor(c0, 1);  c0 += __shfl_xor(c0, 2);  c0 += __shfl_xor(c0, 4);
    c0 += __shfl_xor(c0, 8);  c0 += __shfl_xor(c0, 16); c0 += __shfl_xor(c0, 32);
    if ((tid & 63) == 0) atomicAdd(&csum, c0);
    __syncthreads();
    if (tid == 0) ncnt[p] = (csum < MAXDEG) ? csum : MAXDEG;
}

// Round 19
// 191.202 us; speedup vs baseline: 1.0447x; 1.0143x over previous
//
#include <hip/hip_runtime.h>

#define NN 4096
#define DD 128
#define BB 128
#define QQ 5
#define MAXDEG 96
#define SRCF 0x40000000
#define HP 136   // ushort pitch for bf16 operand buffers: 272B rows -> +4 banks/row
#define FP 132   // float pitch for f32 operand buffers: 528B rows -> +4 banks/row
#define CCAP 1024 // LDS-resident compact correction entries (8 KB)

typedef __attribute__((ext_vector_type(8))) short bf16x8;
typedef __attribute__((ext_vector_type(4))) float f32x4;

// LDS-only barrier: order ds ops, sync waves, never drain vmcnt.
#define LBAR() do { asm volatile("s_waitcnt lgkmcnt(0)" ::: "memory"); \
                    __builtin_amdgcn_sched_barrier(0); \
                    __builtin_amdgcn_s_barrier(); \
                    __builtin_amdgcn_sched_barrier(0); } while (0)

__device__ __forceinline__ float dot4f(float4 a, float4 b) {
    return a.x*b.x + a.y*b.y + a.z*b.z + a.w*b.w;
}
__device__ __forceinline__ unsigned short bfr(float x) {
    unsigned u = __float_as_uint(x);
    return (unsigned short)((u + 0x7fffu + ((u >> 16) & 1u)) >> 16);
}
__device__ __forceinline__ unsigned int pack2bf(float lo, float hi) {
    return ((unsigned int)bfr(hi) << 16) | (unsigned int)bfr(lo);
}

// ---------------- Whz0[n][d] = z0[n].Wh[d] + bh[d] ----------------
__global__ __launch_bounds__(512) void whz_init(
    const float* __restrict__ z0, const float* __restrict__ Wh, const float* __restrict__ bh,
    float* __restrict__ Whz0)
{
    const int t   = threadIdx.x;
    const int rep = t & 7;
    const int d0  = t >> 3;
    float4 wh0[4], wh1[4];
    #pragma unroll
    for (int m = 0; m < 4; ++m) {
        wh0[m] = *(const float4*)(Wh + (size_t)d0*DD + rep*16 + m*4);
        wh1[m] = *(const float4*)(Wh + (size_t)(d0+64)*DD + rep*16 + m*4);
    }
    const float bh0 = bh[d0], bh1 = bh[d0+64];
    const int r0 = blockIdx.x * 16;
    for (int r = r0; r < r0 + 16; ++r) {
        const float* zr = z0 + (size_t)r*DD + rep*16;
        float a0 = 0.f, a1 = 0.f;
        #pragma unroll
        for (int m = 0; m < 4; ++m) {
            float4 zz = *(const float4*)(zr + m*4);
            a0 += dot4f(zz, wh0[m]);
            a1 += dot4f(zz, wh1[m]);
        }
        a0 += __shfl_xor(a0,1); a0 += __shfl_xor(a0,2); a0 += __shfl_xor(a0,4);
        a1 += __shfl_xor(a1,1); a1 += __shfl_xor(a1,2); a1 += __shfl_xor(a1,4);
        if (rep == 0) {
            Whz0[(size_t)r*DD + d0]    = a0 + bh0;
            Whz0[(size_t)r*DD + d0+64] = a1 + bh1;
        }
    }
}

// ---------------- last-update sources for u,v,neg rows ----------------
__global__ void src_kernel(const int* __restrict__ u, const int* __restrict__ v,
                           const int* __restrict__ neg,
                           int* __restrict__ zsrc, int* __restrict__ negsrc)
{
    const int i = blockIdx.x;
    const int k = threadIdx.x;
    if (k >= 2 + 2*QQ) return;
    const int n = (k == 0) ? u[i] : (k == 1) ? v[i] : neg[i*2*QQ + (k-2)];
    int s = n;
    for (int j = i-1; j >= 0; --j) {
        if (v[j] == n) { s = SRCF | (j*2 + 1); break; }
        if (u[j] == n) { s = SRCF | (j*2 + 0); break; }
    }
    if (k < 2) zsrc[i*2 + k] = s;
    else       negsrc[i*2*QQ + (k-2)] = s;
}

// ---------------- FUSED neighbor-list + static-max + corrections + count ----------------
__global__ void nbrprep_kernel(const int* __restrict__ u, const int* __restrict__ v,
                               const float* __restrict__ A, const float* __restrict__ S,
                               const float* __restrict__ Whz0,
                               float* __restrict__ maxpre, int* __restrict__ ncorr,
                               int2* __restrict__ corr_pack, int* __restrict__ ncnt)
{
    __shared__ int   lcnt[257];
    __shared__ int   sidx[MAXDEG];
    __shared__ float sq[MAXDEG];
    __shared__ unsigned char cflag[MAXDEG];
    __shared__ int   su[BB], sv[BB];
    __shared__ float ssum;
    __shared__ int   stot, ccnt;

    const int p    = blockIdx.x;          // (event i, side)
    const int i    = p >> 1;
    const int side = p & 1;
    const int tid  = threadIdx.x;         // 0..255

    const int other = (side == 0) ? v[i] : u[i];   // side0 = agg(v), side1 = agg(u)
    const float* Arow = A + (size_t)other * NN;
    const float* Srow = S + (size_t)other * NN;

    // ---- phase 1: compact neighbor list (deterministic) ----
    const int base = tid * 16;
    int c0 = 0;
    for (int j = 0; j < 16; ++j) c0 += (Arow[base + j] > 0.0f) ? 1 : 0;
    lcnt[tid] = c0;
    if (tid < BB) { su[tid] = u[tid]; sv[tid] = v[tid]; }
    if (tid == 0) ccnt = 0;
    __syncthreads();
    if (tid == 0) {
        int s = 0;
        for (int k = 0; k < 256; ++k) { int c = lcnt[k]; lcnt[k] = s; s += c; }
        stot = s;
    }
    __syncthreads();
    int off = lcnt[tid];
    for (int j = 0; j < 16; ++j) {
        if (Arow[base + j] > 0.0f) {
            if (off < MAXDEG) sidx[off] = base + j;
            ++off;
        }
    }
    __syncthreads();
    const int cnt = (stot < MAXDEG) ? stot : MAXDEG;
    if (tid == 0) ncnt[p] = cnt;                       // count emitted here (r18's cnt_kernel deleted)
    for (int jj = tid; jj < cnt; jj += 256) sq[jj] = expf(Srow[sidx[jj]]);
    __syncthreads();
    if (tid == 0) {
        float s = 0.0f;
        for (int jj = 0; jj < cnt; ++jj) s += sq[jj];
        ssum = s + 1e-7f;
    }
    __syncthreads();
    for (int jj = tid; jj < cnt; jj += 256) sq[jj] = sq[jj] / ssum;
    __syncthreads();

    // ---- phase 2: classify (correction vs static), emit corrections ----
    for (int jj = tid; jj < cnt; jj += 256) {
        const int r = sidx[jj];
        int fs = -1;
        for (int j = i-1; j >= 0; --j) {
            if (sv[j] == r) { fs = j*2 + 1; break; }
            if (su[j] == r) { fs = j*2 + 0; break; }
        }
        if (fs >= 0) {
            const int pos = atomicAdd(&ccnt, 1);   // order-free (commutative max fold)
            int2 cp; cp.x = fs; cp.y = __float_as_int(sq[jj]);
            corr_pack[p*MAXDEG + pos] = cp;
            cflag[jj] = 1;
        } else cflag[jj] = 0;
    }
    __syncthreads();

    // ---- phase 3: static max over never-updated neighbors ----
    if (tid < DD) {
        const int d = tid;
        float m = -3.0e38f;
        for (int jj = 0; jj < cnt; ++jj)
            if (!cflag[jj]) m = fmaxf(m, sq[jj] * Whz0[(size_t)sidx[jj]*DD + d]);
        maxpre[(size_t)p*DD + d] = m;
    }
    if (tid == 0) ncorr[p] = ccnt;
}

// ---------------- sequential scan: 64 paired groups; compaction+pdep in preamble ----------------
__global__ __launch_bounds__(512) void scan_kernel(
    const float* __restrict__ z0, const float* __restrict__ time_diff,
    const int* __restrict__ ncorr, const int2* __restrict__ corr_pack,
    const float* __restrict__ maxpre, const int* __restrict__ zsrc,
    const int* __restrict__ ncnt,
    const float* __restrict__ Wh,  const float* __restrict__ bh,
    const float* __restrict__ Wst, const float* __restrict__ bst,
    const float* __restrict__ Wrc, const float* __restrict__ brc,
    const float* __restrict__ Wt,  const float* __restrict__ bt,
    float* __restrict__ zlog)
{
    __shared__ __align__(16) unsigned short whz_sb[2*BB*DD];   // 64 KB whz log (bf16)
    __shared__ __align__(16) unsigned short zlog_sb[2*BB*DD];  // 64 KB z log (bf16)
    __shared__ __align__(16) unsigned short h_b[4][HP];
    __shared__ __align__(16) unsigned short zrow_b[4][HP];
    __shared__ __align__(16) unsigned short zupdb[4][HP];
    __shared__ __align__(16) float zupd_s[4][FP];
    __shared__ __align__(16) float tdw_s[4][FP];
    __shared__ __align__(16) float tdi_s[BB*8];
    __shared__ __align__(16) int2 corr_lds[CCAP];              // 8 KB compact corrections
    __shared__ int corr_off_s[2*BB + 1];
    __shared__ int cnt_s[2*BB], zsrc_s[2*BB];
    __shared__ int pdep_s[BB/2];
    __shared__ int defflag[4];

    const int t    = threadIdx.x;
    const int wv   = t >> 6;
    const int ln   = t & 63;
    const int arow = wv*16 + (ln & 15);
    const int kgrp = ln >> 4;
    const int ncol = ln & 15;
    const int dbase = wv*16 + kgrp*4;

    // ---- persistent A-fragments (packed bf16 -> remat-proof) ----
    bf16x8 afw[8];   // [Wst | Wrc], K=256
    #pragma unroll
    for (int kt = 0; kt < 8; ++kt) {
        const int kb = kt*32 + kgrp*8;
        const float* src = (kb < 128) ? (Wst + (size_t)arow*DD + kb)
                                      : (Wrc + (size_t)arow*DD + (kb - 128));
        #pragma unroll
        for (int j = 0; j < 8; ++j) afw[kt][j] = (short)bfr(src[j]);
    }
    bf16x8 afh[4];   // Wh, K=128
    #pragma unroll
    for (int kt = 0; kt < 4; ++kt) {
        const float* src = Wh + (size_t)arow*DD + kt*32 + kgrp*8;
        #pragma unroll
        for (int j = 0; j < 8; ++j) afh[kt][j] = (short)bfr(src[j]);
    }
    f32x4 bsv, bhv;
    #pragma unroll
    for (int r = 0; r < 4; ++r) {
        bsv[r] = bst[dbase+r] + brc[dbase+r] + bt[dbase+r];
        bhv[r] = bh[dbase+r];
    }
    const float4 wtA = *(const float4*)(Wt + (size_t)(ln*2)*4);
    const float4 wtB = *(const float4*)(Wt + (size_t)(ln*2+1)*4);

    // ---- preamble A: scalar preloads ----
    if (t < 256)      { cnt_s[t] = ncnt[t]; }
    else              { zsrc_s[t-256] = zsrc[t-256]; }
    if (t < 4)        defflag[t] = 0;
    {
        const float sdv[4] = {50.f, 7.f, 15.f, 15.f};
        for (int e = t; e < BB*8; e += 512) tdi_s[e] = time_diff[e] / sdv[e & 3];
    }
    __syncthreads();

    // ---- preamble B: prefix-scan ncorr (wave 0) -> corr_off_s ----
    if (wv == 0) {
        int n0 = ncorr[ln*4+0], n1 = ncorr[ln*4+1], n2 = ncorr[ln*4+2], n3 = ncorr[ln*4+3];
        int loc = n0 + n1 + n2 + n3;
        int incl = loc;
        #pragma unroll
        for (int s = 1; s < 64; s <<= 1) {
            int up = __shfl_up(incl, s);
            if (ln >= s) incl += up;
        }
        const int bse = incl - loc;
        corr_off_s[ln*4+0] = bse;
        corr_off_s[ln*4+1] = bse + n0;
        corr_off_s[ln*4+2] = bse + n0 + n1;
        corr_off_s[ln*4+3] = bse + n0 + n1 + n2;
        if (ln == 63) corr_off_s[256] = incl;
    }
    __syncthreads();

    // ---- preamble C: gather corrections into LDS ----
    if (t < 256) {
        const int b0 = corr_off_s[t];
        const int nc = corr_off_s[t+1] - b0;
        for (int c = 0; c < nc; ++c) {
            const int idx = b0 + c;
            if (idx < CCAP) corr_lds[idx] = corr_pack[t*MAXDEG + c];
        }
    }
    __syncthreads();

    // ---- preamble D: pair-dependency flags ----
    if (t < BB/2) {
        const int g = t;
        int dep = 0;
        #pragma unroll
        for (int k = 0; k < 2; ++k) {
            const int s = zsrc_s[(2*g+1)*2 + k];
            if ((s & SRCF) && (((s & 0xFFFF) >> 1) == 2*g)) dep = 1;
        }
        #pragma unroll
        for (int k = 0; k < 2; ++k) {
            const int p = (2*g+1)*2 + k;
            const int b0 = corr_off_s[p];
            const int nc = corr_off_s[p+1] - b0;
            for (int c = 0; c < nc; ++c) {
                const int idx = b0 + c;
                const int2 e = (idx < CCAP) ? corr_lds[idx] : corr_pack[p*MAXDEG + c];
                if ((e.x >> 1) == 2*g) dep = 1;
            }
        }
        pdep_s[g] = dep;
    }
    __syncthreads();

    // ---- wave-private pipeline state ----
    float2 mwork = make_float2(0.f, 0.f);
    float2 mnext = make_float2(0.f, 0.f);
    int2 de0, de1, de2, de3; int ndefr = 0;
    int2 ie0, ie1;           int nintra = 0;
    float2 zn2 = make_float2(0.f, 0.f);

    // ================= helper lambdas =================
    auto DO_P1 = [&]() {
        const int cc = (ncol < 4) ? ncol : 0;
        const unsigned short* hp = &h_b[cc][0];
        const unsigned short* zp = &zrow_b[cc][0];
        f32x4 accA = {0.f,0.f,0.f,0.f}, accB = {0.f,0.f,0.f,0.f};
        __builtin_amdgcn_s_setprio(1);
        #pragma unroll
        for (int kt = 0; kt < 4; kt += 2) {
            bf16x8 b0 = *(const bf16x8*)&hp[kt*32 + kgrp*8];
            bf16x8 b1 = *(const bf16x8*)&hp[(kt+1)*32 + kgrp*8];
            accA = __builtin_amdgcn_mfma_f32_16x16x32_bf16(afw[kt],   b0, accA, 0,0,0);
            accB = __builtin_amdgcn_mfma_f32_16x16x32_bf16(afw[kt+1], b1, accB, 0,0,0);
        }
        #pragma unroll
        for (int kt = 4; kt < 8; kt += 2) {
            bf16x8 b0 = *(const bf16x8*)&zp[(kt-4)*32 + kgrp*8];
            bf16x8 b1 = *(const bf16x8*)&zp[(kt-3)*32 + kgrp*8];
            accA = __builtin_amdgcn_mfma_f32_16x16x32_bf16(afw[kt],   b0, accA, 0,0,0);
            accB = __builtin_amdgcn_mfma_f32_16x16x32_bf16(afw[kt+1], b1, accB, 0,0,0);
        }
        __builtin_amdgcn_s_setprio(0);
        if (ncol < 4) {
            const f32x4 tdwv = *(const f32x4*)&tdw_s[ncol][dbase];
            f32x4 zu4;
            #pragma unroll
            for (int r = 0; r < 4; ++r) {
                const float a = accA[r] + accB[r] + bsv[r] + tdwv[r];
                zu4[r] = 1.0f/(1.0f + __expf(-a));
            }
            *(f32x4*)&zupd_s[ncol][dbase] = zu4;
            uint2 pk;
            pk.x = pack2bf(zu4[0], zu4[1]);
            pk.y = pack2bf(zu4[2], zu4[3]);
            *(uint2*)&zupdb[ncol][dbase] = pk;
        }
    };

    auto DO_P2 = [&](int writeAll, int G) {
        const int cc = (ncol < 4) ? ncol : 0;
        const unsigned short* up = &zupdb[cc][0];
        f32x4 accA = {0.f,0.f,0.f,0.f}, accB = {0.f,0.f,0.f,0.f};
        __builtin_amdgcn_s_setprio(1);
        {
            bf16x8 b0 = *(const bf16x8*)&up[0*32 + kgrp*8];
            bf16x8 b1 = *(const bf16x8*)&up[1*32 + kgrp*8];
            bf16x8 b2 = *(const bf16x8*)&up[2*32 + kgrp*8];
            bf16x8 b3 = *(const bf16x8*)&up[3*32 + kgrp*8];
            accA = __builtin_amdgcn_mfma_f32_16x16x32_bf16(afh[0], b0, accA, 0,0,0);
            accB = __builtin_amdgcn_mfma_f32_16x16x32_bf16(afh[1], b1, accB, 0,0,0);
            accA = __builtin_amdgcn_mfma_f32_16x16x32_bf16(afh[2], b2, accA, 0,0,0);
            accB = __builtin_amdgcn_mfma_f32_16x16x32_bf16(afh[3], b3, accB, 0,0,0);
        }
        __builtin_amdgcn_s_setprio(0);
        if (ncol < 4 && (writeAll || ncol < 2)) {
            const int row = 4*G + ncol;
            uint2 wpk;
            wpk.x = pack2bf(accA[0]+accB[0]+bhv[0], accA[1]+accB[1]+bhv[1]);
            wpk.y = pack2bf(accA[2]+accB[2]+bhv[2], accA[3]+accB[3]+bhv[3]);
            *(uint2*)&whz_sb[row*DD + dbase] = wpk;
            const f32x4 zu4 = *(const f32x4*)&zupd_s[ncol][dbase];
            uint2 zpk;
            zpk.x = pack2bf(zu4[0], zu4[1]);
            zpk.y = pack2bf(zu4[2], zu4[3]);
            *(uint2*)&zlog_sb[row*DD + dbase] = zpk;
        }
    };

    // Prepare pair curG+1 = steps {C, C+1}; corrections read from LDS.
    auto PREP = [&](int curG) {
        const int C = 2*curG + 2;
        if (C >= BB) return;
        if (wv < 4) {
            const int step = C + (wv >> 1);
            const int side = wv & 1;
            const int p1 = step*2 + side;
            const int cbase = corr_off_s[p1];
            const int nc = corr_off_s[p1+1] - cbase;
            float2 m = mnext;
            int nd = 0, ni = 0;
            int2 dl0, dl1, dl2, dl3, il0, il1;
            for (int c = 0; c < nc; ++c) {
                const int idx = cbase + c;
                const int2 e = (idx < CCAP) ? corr_lds[idx] : corr_pack[p1*MAXDEG + c];
                if ((e.x >> 2) == curG) {                       // src in current pair -> defer
                    if (nd==0) dl0=e; else if (nd==1) dl1=e; else if (nd==2) dl2=e; else dl3=e;
                    ++nd;
                } else if ((e.x >> 1) == C && step == C+1) {    // intra-next-pair
                    if (ni==0) il0=e; else il1=e;
                    ++ni;
                } else {
                    const float qc = __int_as_float(e.y);
                    const unsigned pk = *(const unsigned*)&whz_sb[e.x*DD + ln*2];
                    m.x = fmaxf(m.x, qc * __uint_as_float(pk << 16));
                    m.y = fmaxf(m.y, qc * __uint_as_float(pk & 0xffff0000u));
                }
            }
            mwork = m; ndefr = nd; nintra = ni;
            de0=dl0; de1=dl1; de2=dl2; de3=dl3; ie0=il0; ie1=il1;
            if (nd == 0 && ni == 0) {
                float h0 = 0.f, h1 = 0.f;
                if (cnt_s[p1] > 0) {
                    h0 = 1.0f/(1.0f + __expf(-m.x));
                    h1 = 1.0f/(1.0f + __expf(-m.y));
                }
                *(unsigned*)&h_b[wv][ln*2] = pack2bf(h0, h1);
            }
            if (ln == 0) defflag[wv] = nd;
            const int Cn = C + 2;
            const int stepn = (Cn + (wv>>1) < BB) ? (Cn + (wv>>1)) : step;
            const int pn = stepn*2 + side;
            mnext = *(const float2*)&maxpre[(size_t)pn*DD + ln*2];
        } else {
            const int k = wv - 4;
            const int step = C + (k >> 1);
            const int uvk = k & 1;
            const int s = zsrc_s[step*2 + uvk];
            if (s & SRCF) {
                const int row = s & 0xFFFF;
                const int rg  = row >> 2;
                if (rg == curG) {
                    const float2 zf = *(const float2*)&zupd_s[row & 3][ln*2];
                    *(unsigned*)&zrow_b[k][ln*2] = pack2bf(zf.x, zf.y);
                } else if (rg < curG) {
                    *(unsigned*)&zrow_b[k][ln*2] = *(const unsigned*)&zlog_sb[row*DD + ln*2];
                }
                // rg == curG+1 (B references A of the NEXT pair): slow path republishes
            } else {
                *(unsigned*)&zrow_b[k][ln*2] = pack2bf(zn2.x, zn2.y);
            }
            if (wv == 4) {
                const float* tp = &tdi_s[C*8];
                tdw_s[0][ln*2]   = tp[0]*wtA.x + tp[1]*wtA.y + tp[2]*wtA.z + tp[3]*wtA.w;
                tdw_s[0][ln*2+1] = tp[0]*wtB.x + tp[1]*wtB.y + tp[2]*wtB.z + tp[3]*wtB.w;
                tdw_s[1][ln*2]   = tp[4]*wtA.x + tp[5]*wtA.y + tp[6]*wtA.z + tp[7]*wtA.w;
                tdw_s[1][ln*2+1] = tp[4]*wtB.x + tp[5]*wtB.y + tp[6]*wtB.z + tp[7]*wtB.w;
            } else if (wv == 5) {
                const float* tp = &tdi_s[(C+1)*8];
                tdw_s[2][ln*2]   = tp[0]*wtA.x + tp[1]*wtA.y + tp[2]*wtA.z + tp[3]*wtA.w;
                tdw_s[2][ln*2+1] = tp[0]*wtB.x + tp[1]*wtB.y + tp[2]*wtB.z + tp[3]*wtB.w;
                tdw_s[3][ln*2]   = tp[4]*wtA.x + tp[5]*wtA.y + tp[6]*wtA.z + tp[7]*wtA.w;
                tdw_s[3][ln*2+1] = tp[4]*wtB.x + tp[5]*wtB.y + tp[6]*wtB.z + tp[7]*wtB.w;
            }
            const int Cn = C + 2;
            if (Cn + (k>>1) < BB) {
                const int sn = zsrc_s[(Cn + (k>>1))*2 + uvk];
                if (!(sn & SRCF)) zn2 = *(const float2*)&z0[(size_t)sn*DD + ln*2];
            }
        }
    };

    // ---- priming: prefetch + prepare pair 0 ----
    if (wv < 4) {
        const int p0 = (wv >> 1)*2 + (wv & 1);
        mnext = *(const float2*)&maxpre[(size_t)p0*DD + ln*2];
    } else {
        const int k = wv - 4;
        const int s = zsrc_s[(k >> 1)*2 + (k & 1)];
        if (!(s & SRCF)) zn2 = *(const float2*)&z0[(size_t)s*DD + ln*2];
    }
    PREP(-1);
    LBAR();

    // ================= main loop over 64 pairs =================
    for (int G = 0; G < BB/2; ++G) {
        // ---- FIXUP: fold deferred cross-pair corrections ----
        if (defflag[0] | defflag[1] | defflag[2] | defflag[3]) {
            if (wv < 4 && ndefr) {
                float2 m = mwork;
                {
                    const float qc = __int_as_float(de0.y);
                    const unsigned pk = *(const unsigned*)&whz_sb[de0.x*DD + ln*2];
                    m.x = fmaxf(m.x, qc * __uint_as_float(pk << 16));
                    m.y = fmaxf(m.y, qc * __uint_as_float(pk & 0xffff0000u));
                }
                if (ndefr > 1) {
                    const float qc = __int_as_float(de1.y);
                    const unsigned pk = *(const unsigned*)&whz_sb[de1.x*DD + ln*2];
                    m.x = fmaxf(m.x, qc * __uint_as_float(pk << 16));
                    m.y = fmaxf(m.y, qc * __uint_as_float(pk & 0xffff0000u));
                }
                if (ndefr > 2) {
                    const float qc = __int_as_float(de2.y);
                    const unsigned pk = *(const unsigned*)&whz_sb[de2.x*DD + ln*2];
                    m.x = fmaxf(m.x, qc * __uint_as_float(pk << 16));
                    m.y = fmaxf(m.y, qc * __uint_as_float(pk & 0xffff0000u));
                }
                if (ndefr > 3) {
                    const float qc = __int_as_float(de3.y);
                    const unsigned pk = *(const unsigned*)&whz_sb[de3.x*DD + ln*2];
                    m.x = fmaxf(m.x, qc * __uint_as_float(pk << 16));
                    m.y = fmaxf(m.y, qc * __uint_as_float(pk & 0xffff0000u));
                }
                mwork = m; ndefr = 0;
                if (nintra == 0) {
                    const int p1 = (2*G + (wv>>1))*2 + (wv & 1);
                    float h0 = 0.f, h1 = 0.f;
                    if (cnt_s[p1] > 0) {
                        h0 = 1.0f/(1.0f + __expf(-m.x));
                        h1 = 1.0f/(1.0f + __expf(-m.y));
                    }
                    *(unsigned*)&h_b[wv][ln*2] = pack2bf(h0, h1);
                }
            }
            LBAR();
        }

        if (!pdep_s[G]) {
            // -------- fast path: 2 phases for 2 steps --------
            DO_P1();
            LBAR();
            DO_P2(1, G);
            PREP(G);
            LBAR();
        } else {
            // -------- slow path: step A then step B --------
            DO_P1();
            LBAR();
            DO_P2(0, G);
            if (wv >= 6) {
                const int k = wv - 4;
                const int s = zsrc_s[(2*G+1)*2 + (k & 1)];
                if ((s & SRCF) && (((s & 0xFFFF) >> 2) == G)) {
                    const int row = s & 0xFFFF;
                    const float2 zf = *(const float2*)&zupd_s[row & 3][ln*2];
                    *(unsigned*)&zrow_b[k][ln*2] = pack2bf(zf.x, zf.y);
                }
            }
            LBAR();
            if ((wv == 2 || wv == 3) && nintra) {
                float2 m = mwork;
                {
                    const float qc = __int_as_float(ie0.y);
                    const unsigned pk = *(const unsigned*)&whz_sb[ie0.x*DD + ln*2];
                    m.x = fmaxf(m.x, qc * __uint_as_float(pk << 16));
                    m.y = fmaxf(m.y, qc * __uint_as_float(pk & 0xffff0000u));
                }
                if (nintra > 1) {
                    const float qc = __int_as_float(ie1.y);
                    const unsigned pk = *(const unsigned*)&whz_sb[ie1.x*DD + ln*2];
                    m.x = fmaxf(m.x, qc * __uint_as_float(pk << 16));
                    m.y = fmaxf(m.y, qc * __uint_as_float(pk & 0xffff0000u));
                }
                const int p1 = (2*G+1)*2 + (wv & 1);
                float h0 = 0.f, h1 = 0.f;
                if (cnt_s[p1] > 0) {
                    h0 = 1.0f/(1.0f + __expf(-m.x));
                    h1 = 1.0f/(1.0f + __expf(-m.y));
                }
                *(unsigned*)&h_b[wv][ln*2] = pack2bf(h0, h1);
                nintra = 0;
            }
            LBAR();
            DO_P1();
            LBAR();
            DO_P2(1, G);
            PREP(G);
            LBAR();
        }
    }

    // ---- batched zlog dump (only global store in the kernel) ----
    for (int e = t; e < BB*DD; e += 512) {
        const unsigned pk = *(const unsigned*)&zlog_sb[e*2];
        float2 val;
        val.x = __uint_as_float(pk << 16);
        val.y = __uint_as_float(pk & 0xffff0000u);
        *(float2*)&zlog[(size_t)e*2] = val;
    }
}

// ---------------- intensity epilogue (parallel, reads via src indices) ----------------
__global__ void lam_kernel(const float* __restrict__ z0, const float* __restrict__ zlog,
                           const int* __restrict__ zsrc, const int* __restrict__ negsrc,
                           const int* __restrict__ et,
                           const float* __restrict__ w0, const float* __restrict__ b0,
                           const float* __restrict__ w1, const float* __restrict__ b1,
                           const float* __restrict__ psi,
                           float* __restrict__ out)
{
    const int b   = blockIdx.x;
    const int i   = b / 11;
    const int col = b % 11;
    const int l   = threadIdx.x;

    auto rp = [&](int s) -> const float* {
        return (s & SRCF) ? (zlog + (size_t)(s & 0xFFFF)*DD) : (z0 + (size_t)s*DD);
    };
    const float* xu;
    const float* xv;
    if (col == 0) { xu = rp(zsrc[i*2]); xv = rp(zsrc[i*2+1]); }
    else {
        const int k = col - 1;
        xu = (k < QQ) ? rp(zsrc[i*2])            : rp(negsrc[i*2*QQ + k]);
        xv = (k < QQ) ? rp(negsrc[i*2*QQ + k])   : rp(zsrc[i*2+1]);
    }
    float g0 = xu[l]*w0[l] + xu[l+64]*w0[l+64] + xv[l]*w0[DD+l] + xv[l+64]*w0[DD+l+64];
    float g1 = xu[l]*w1[l] + xu[l+64]*w1[l+64] + xv[l]*w1[DD+l] + xv[l+64]*w1[DD+l+64];
    #pragma unroll
    for (int s = 32; s >= 1; s >>= 1) { g0 += __shfl_xor(g0, s); g1 += __shfl_xor(g1, s); }
    if (l == 0) {
        g0 += b0[0]; g1 += b1[0];
        const float p0 = psi[0], p1 = psi[1];
        float r;
        if (col == 0) {
            const int e = et[i];
            const float g = e ? g1 : g0;
            const float p = e ? p1 : p0;
            const float y = g / (p + 1e-7f);
            r = p * (fmaxf(y, 0.f) + log1pf(expf(-fabsf(y))));
        } else {
            const float y0 = g0 / (p0 + 1e-7f);
            const float y1 = g1 / (p1 + 1e-7f);
            r = p0 * (fmaxf(y0, 0.f) + log1pf(expf(-fabsf(y0))))
              + p1 * (fmaxf(y1, 0.f) + log1pf(expf(-fabsf(y1))));
        }
        out[i*11 + col] = r;
    }
}

extern "C" void kernel_launch(void* const* d_in, const int* in_sizes, int n_in,
                              void* d_out, int out_size, void* d_ws, size_t ws_size,
                              hipStream_t stream)
{
    const int*   u   = (const int*)d_in[0];
    const int*   v   = (const int*)d_in[1];
    const int*   et  = (const int*)d_in[2];
    const float* td  = (const float*)d_in[3];
    const int*   neg = (const int*)d_in[4];
    const float* z0  = (const float*)d_in[5];
    const float* A   = (const float*)d_in[6];
    const float* S   = (const float*)d_in[7];
    const float* w0  = (const float*)d_in[8];
    const float* b0  = (const float*)d_in[9];
    const float* w1  = (const float*)d_in[10];
    const float* b1  = (const float*)d_in[11];
    const float* psi = (const float*)d_in[12];
    const float* Wh  = (const float*)d_in[13];
    const float* bh  = (const float*)d_in[14];
    const float* Wst = (const float*)d_in[15];
    const float* bst = (const float*)d_in[16];
    const float* Wrc = (const float*)d_in[17];
    const float* brc = (const float*)d_in[18];
    const float* Wt  = (const float*)d_in[19];
    const float* bt  = (const float*)d_in[20];

    char* ws = (char*)d_ws;
    size_t off = 0;
    auto alloc = [&](size_t bytes) {
        void* p = ws + off;
        off = (off + bytes + 255) & ~(size_t)255;
        return p;
    };
    float* Whz0   = (float*)alloc((size_t)NN*DD*sizeof(float));
    float* maxpre = (float*)alloc((size_t)2*BB*DD*sizeof(float));
    float* zlog   = (float*)alloc((size_t)2*BB*DD*sizeof(float));
    int*   ncnt   = (int*)alloc((size_t)2*BB*sizeof(int));
    int*   ncorr  = (int*)alloc((size_t)2*BB*sizeof(int));
    int2*  cpk    = (int2*)alloc((size_t)2*BB*MAXDEG*sizeof(int2));
    int*   zsrc   = (int*)alloc((size_t)2*BB*sizeof(int));
    int*   negsrc = (int*)alloc((size_t)BB*2*QQ*sizeof(int));

    whz_init<<<NN/16, 512, 0, stream>>>(z0, Wh, bh, Whz0);
    src_kernel<<<BB, 64, 0, stream>>>(u, v, neg, zsrc, negsrc);
    nbrprep_kernel<<<2*BB, 256, 0, stream>>>(u, v, A, S, Whz0, maxpre, ncorr, cpk, ncnt);
    scan_kernel<<<1, 512, 0, stream>>>(z0, td, ncorr, cpk, maxpre, zsrc, ncnt,
                                       Wh, bh, Wst, bst, Wrc, brc, Wt, bt, zlog);
    lam_kernel<<<BB*(1 + 2*QQ), 64, 0, stream>>>(z0, zlog, zsrc, negsrc, et,
                                                 w0, b0, w1, b1, psi, (float*)d_out);
}